// Round 7
// baseline (1135.216 us; speedup 1.0000x reference)
//
#include <hip/hip_runtime.h>
#include <hip/hip_fp16.h>

#define NN 100000
#define NE 3200000
#define DD 256
#define NT 8192
#define NOUT 10
#define NBUCK 196        // ceil(100000/512) buckets of 512 dst nodes
// per bucket: edges + 512 self + <=512*7 pad + 8 align slack
#define CSRP_CAP (NE + NBUCK * 4112 + 64)

typedef unsigned short u16;
typedef unsigned int u32;
typedef unsigned char u8;
typedef __attribute__((ext_vector_type(8))) short bf16x8;
typedef __attribute__((ext_vector_type(4))) float f32x4;
typedef __attribute__((ext_vector_type(4))) unsigned int uint4v;

__device__ __forceinline__ float bf2f(u16 u) {
    union { unsigned int i; float f; } v; v.i = ((unsigned int)u) << 16; return v.f;
}
__device__ __forceinline__ u16 f2bf(float f) {
    union { float f; unsigned int i; } v; v.f = f;
    unsigned int x = v.i;
    return (u16)((x + 0x7fffu + ((x >> 16) & 1u)) >> 16);
}
__device__ __forceinline__ unsigned int pack2(float a, float b) {
    return (unsigned int)f2bf(a) | ((unsigned int)f2bf(b) << 16);
}
// pack src(17b) | fp16-no-sign(15b); w>0 always
__device__ __forceinline__ u32 packrec(int src, float w) {
    unsigned short h = __half_as_ushort(__float2half(w));
    return ((u32)src << 15) | (u32)(h & 0x7fff);
}
__device__ __forceinline__ float recw(u32 r) {
    return __half2float(__ushort_as_half((unsigned short)(r & 0x7fff)));
}

__device__ __forceinline__ void gl2lds16(const void* g, void* l) {
    __builtin_amdgcn_global_load_lds(
        (const __attribute__((address_space(1))) unsigned int*)g,
        (__attribute__((address_space(3))) unsigned int*)l, 16, 0, 0);
}

// ---- weight convert + transpose: Wt[l][n][k] = bf16(W[l][k][n]) ----
// block 0 also zeroes bucketCnt (saves a dispatch)
__global__ __launch_bounds__(256) void k_wt(const float* __restrict__ gW,
                                            const float* __restrict__ lW,
                                            u16* __restrict__ Wt,
                                            int* __restrict__ bucketCnt) {
    if (blockIdx.x == 0 && threadIdx.x < NBUCK) bucketCnt[threadIdx.x] = 0;
    int idx = blockIdx.x * 256 + threadIdx.x;      // < 6*65536
    int l = idx >> 16;
    int nk = idx & 65535;
    int n = nk >> 8, k = nk & 255;
    float v = (l < 4) ? gW[l * 65536 + k * 256 + n]
                      : lW[(l - 4) * 65536 + k * 256 + n];
    Wt[idx] = f2bf(v);
}

// ---- pass A: per-bucket edge counts ----
__global__ __launch_bounds__(256) void k_binA(const int* __restrict__ dst,
                                              int* __restrict__ bucketCnt) {
    __shared__ int hist[NBUCK];
    int t = threadIdx.x;
    if (t < NBUCK) hist[t] = 0;
    __syncthreads();
    int base = blockIdx.x * 4096;
#pragma unroll
    for (int i = 0; i < 16; i++) {
        int e = base + i * 256 + t;
        if (e < NE) atomicAdd(&hist[dst[e] >> 9], 1);
    }
    __syncthreads();
    if (t < NBUCK && hist[t] > 0) atomicAdd(&bucketCnt[t], hist[t]);
}

// ---- scan bucket counts -> bucketOff (stable) + bucketCur (cursor) ----
__global__ __launch_bounds__(256) void k_bscan(const int* __restrict__ bucketCnt,
                                               int* __restrict__ bucketOff,
                                               int* __restrict__ bucketCur) {
    __shared__ int s[256];
    int t = threadIdx.x;
    int v = (t < NBUCK) ? bucketCnt[t] : 0;
    s[t] = v;
    __syncthreads();
    for (int o = 1; o < 256; o <<= 1) {
        int a = (t >= o) ? s[t - o] : 0;
        __syncthreads();
        s[t] += a;
        __syncthreads();
    }
    if (t < NBUCK) {
        int ex = s[t] - v;
        bucketOff[t] = ex;
        bucketCur[t] = ex;
    }
    if (t == 0) bucketOff[NBUCK] = NE;
}

// ---- pass B: write records at ABSOLUTE bucket offsets ----
// record = (src << 9) | (dst & 511)   (src < 2^17)
__global__ __launch_bounds__(1024) void k_binB(const int* __restrict__ src,
                                               const int* __restrict__ dst,
                                               int* __restrict__ bucketCur,
                                               int* __restrict__ recs) {
    __shared__ int hist[NBUCK];
    __shared__ int gbase[NBUCK];
    int t = threadIdx.x;
    if (t < NBUCK) hist[t] = 0;
    __syncthreads();
    int base = blockIdx.x * 16384;
    int recv[16], bks[16], rnk[16];
#pragma unroll
    for (int i = 0; i < 16; i++) {
        int e = base + i * 1024 + t;
        int bk = -1, rec = 0;
        if (e < NE) {
            int s_ = src[e], d_ = dst[e];
            bk = d_ >> 9;
            rec = (s_ << 9) | (d_ & 511);
        }
        bks[i] = bk; recv[i] = rec;
    }
#pragma unroll
    for (int i = 0; i < 16; i++)
        rnk[i] = (bks[i] >= 0) ? atomicAdd(&hist[bks[i]], 1) : 0;
    __syncthreads();
    if (t < NBUCK) {
        int c = hist[t];
        gbase[t] = (c > 0) ? atomicAdd(&bucketCur[t], c) : 0;  // absolute
    }
    __syncthreads();
#pragma unroll
    for (int i = 0; i < 16; i++)
        if (bks[i] >= 0) {
            int pos = gbase[bks[i]] + rnk[i];
            pos = min(max(pos, 0), NE - 1);
            recs[pos] = recv[i];
        }
}

// ---- csrA: per-bucket count + padded scan -> nodeInfo/dinv/self/dummies ----
// csrp record = u32 (src<<15)|fp16w; per node: [self][edges...][dummies] pad 8
// NOTE: must be a SEPARATE dispatch from csrB — csrB reads dinv[s] for
// arbitrary s (cross-bucket); merging creates a cross-workgroup RAW race (R9).
__global__ __launch_bounds__(256) void k_csrA(const int* __restrict__ recs,
                                              const int* __restrict__ bucketOff,
                                              int2* __restrict__ nodeInfo,
                                              float* __restrict__ dinv,
                                              u32* __restrict__ csrp) {
    __shared__ int cnt[512], off[512];
    int b = blockIdx.x, t = threadIdx.x;
    int beg = min(max(bucketOff[b], 0), NE);
    int end = min(max(bucketOff[b + 1], beg), NE);
    int n = end - beg;
    cnt[t] = 0; cnt[t + 256] = 0;
    __syncthreads();
    for (int i = t; i < n; i += 256)
        atomicAdd(&cnt[recs[beg + i] & 511], 1);
    __syncthreads();
    off[t] = (cnt[t] + 8) & ~7;            // padded size: cnt+1 self, round to 8
    off[t + 256] = (cnt[t + 256] + 8) & ~7;
    __syncthreads();
    for (int o = 1; o < 512; o <<= 1) {
        int v0 = (t >= o) ? off[t - o] : 0;
        int v1 = (t + 256 >= o) ? off[t + 256 - o] : 0;
        __syncthreads();
        off[t] += v0; off[t + 256] += v1;
        __syncthreads();
    }
    int base = (beg + b * 4112 + 7) & ~7;  // 8-record aligned bucket region
    for (int k = t; k < 512; k += 256) {
        int node = b * 512 + k;
        if (node >= NN) continue;
        int pd = (cnt[k] + 8) & ~7;
        int nbeg = base + off[k] - pd;     // exclusive padded scan (8-aligned)
        int2 ni; ni.x = nbeg; ni.y = pd;
        nodeInfo[node] = ni;
        float di = rsqrtf((float)(cnt[k] + 1));
        dinv[node] = di;
        csrp[nbeg] = packrec(node, di * di);
        for (int j = nbeg + 1 + cnt[k]; j < nbeg + pd; j++) csrp[j] = 0u;
    }
}

// ---- csrB: scatter edges with precomputed fp16 weight ----
__global__ __launch_bounds__(256) void k_csrB(const int* __restrict__ recs,
                                              const int* __restrict__ bucketOff,
                                              const int2* __restrict__ nodeInfo,
                                              const float* __restrict__ dinv,
                                              u32* __restrict__ csrp) {
    __shared__ int cur[512];
    int b = blockIdx.x, t = threadIdx.x;
    cur[t] = 0; cur[t + 256] = 0;
    __syncthreads();
    int beg = min(max(bucketOff[b], 0), NE);
    int end = min(max(bucketOff[b + 1], beg), NE);
    int n = end - beg;
    for (int i = t; i < n; i += 256) {
        int r = recs[beg + i];
        int dlow = r & 511;
        int s = min(max(r >> 9, 0), NN - 1);
        int node = b * 512 + dlow;
        int rk = atomicAdd(&cur[dlow], 1);
        int2 ni = nodeInfo[node];
        float w = dinv[s] * dinv[node];
        int pos = ni.x + 1 + rk;
        pos = min(max(pos, 0), CSRP_CAP - 1);
        csrp[pos] = packrec(s, w);
    }
}

// ---- shared GEMM epilogue (bf16 C) — lin-layer 128x128 kernels ----
#define GEMM_EPILOGUE                                                         \
    for (int i = 0; i < 4; i++)                                               \
        for (int j = 0; j < 4; j++) {                                         \
            int col = colBase + wn * 64 + j * 16 + l16;                       \
            for (int r = 0; r < 4; r++) {                                     \
                int row = rowBase + wm * 64 + i * 16 + quad * 4 + r;          \
                if (row < M) C[row * 256 + col] = f2bf(acc[i][j][r]);         \
            }                                                                 \
        }

#define GEMM_COMPUTE(ASRC, BSRC)                                              \
    for (int ks = 0; ks < 2; ks++) {                                          \
        bf16x8 a_frag[4], b_frag[4];                                          \
        for (int i = 0; i < 4; i++) {                                         \
            int r = wm * 64 + i * 16 + l16;                                   \
            int ch = (ks * 4 + quad) ^ (r & 7);                               \
            a_frag[i] = *(const bf16x8*)(&ASRC[r * 64 + ch * 8]);             \
        }                                                                     \
        for (int j = 0; j < 4; j++) {                                         \
            int r = wn * 64 + j * 16 + l16;                                   \
            int ch = (ks * 4 + quad) ^ (r & 7);                               \
            b_frag[j] = *(const bf16x8*)(&BSRC[r * 64 + ch * 8]);             \
        }                                                                     \
        for (int i = 0; i < 4; i++)                                           \
            for (int j = 0; j < 4; j++)                                       \
                acc[i][j] = __builtin_amdgcn_mfma_f32_16x16x32_bf16(          \
                    a_frag[i], b_frag[j], acc[i][j], 0, 0, 0);                \
    }

// ---- bf16 MFMA GEMM (bf16 C out) — lin layers, 128x128 tile ----
__global__ __launch_bounds__(256) void k_gemm(const u16* __restrict__ A,
                                              const u16* __restrict__ Bt,
                                              u16* __restrict__ C, int M) {
    __shared__ __align__(16) u16 As[128 * 64];
    __shared__ __align__(16) u16 Bs[128 * 64];
    const int tid = threadIdx.x;
    const int wave = tid >> 6, lane = tid & 63;
    const int wm = wave >> 1, wn = wave & 1;
    const int rowBase = blockIdx.x * 128;
    const int colBase = blockIdx.y * 128;
    const int quad = lane >> 4, l16 = lane & 15;

    f32x4 acc[4][4] = {};

    for (int kk = 0; kk < 4; kk++) {
        int k0 = kk * 64;
#pragma unroll
        for (int i = 0; i < 4; i++) {
            int j = (i * 4 + wave) * 64 + lane;    // task 0..1023
            int r = j >> 3, c = j & 7;
            int cg = c ^ (r & 7);                  // source-chunk swizzle
            int ga = rowBase + r; if (ga >= M) ga = M - 1;
            gl2lds16(A + (size_t)ga * 256 + k0 + cg * 8,
                     &As[(i * 4 + wave) * 512]);
            gl2lds16(Bt + (size_t)(colBase + r) * 256 + k0 + cg * 8,
                     &Bs[(i * 4 + wave) * 512]);
        }
        __syncthreads();
        GEMM_COMPUTE(As, Bs)
        __syncthreads();
    }
    GEMM_EPILOGUE
}

// ---- GNN GEMM v2: 128x256 tile, 8 waves, B fully in REGISTERS (128 VGPR),
// A streamed global->VGPR. No LDS in compute loop, no barriers until the
// quant epilogue. Fused int8-quant output (single per-row scale). ----
#define GQ_EPILOGUE(Q8, QS)                                                   \
    {                                                                         \
        /* per-wave partial rowmax over its 64 cols */                        \
        for (int i = 0; i < 4; i++) {                                         \
            float m0 = 0.f, m1 = 0.f, m2 = 0.f, m3 = 0.f;                     \
            for (int j = 0; j < 4; j++) {                                     \
                m0 = fmaxf(m0, fabsf(acc[i][j][0]));                          \
                m1 = fmaxf(m1, fabsf(acc[i][j][1]));                          \
                m2 = fmaxf(m2, fabsf(acc[i][j][2]));                          \
                m3 = fmaxf(m3, fabsf(acc[i][j][3]));                          \
            }                                                                 \
            for (int o = 1; o < 16; o <<= 1) {                                \
                m0 = fmaxf(m0, __shfl_xor(m0, o, 64));                        \
                m1 = fmaxf(m1, __shfl_xor(m1, o, 64));                        \
                m2 = fmaxf(m2, __shfl_xor(m2, o, 64));                        \
                m3 = fmaxf(m3, __shfl_xor(m3, o, 64));                        \
            }                                                                 \
            if (l16 == 0) {                                                   \
                int rl = wr * 64 + i * 16 + quad * 4;                         \
                rmax[wc][rl + 0] = m0; rmax[wc][rl + 1] = m1;                 \
                rmax[wc][rl + 2] = m2; rmax[wc][rl + 3] = m3;                 \
            }                                                                 \
        }                                                                     \
        __syncthreads();                                                      \
        for (int i = 0; i < 4; i++) {                                         \
            int rl = wr * 64 + i * 16 + quad * 4;                             \
            for (int r = 0; r < 4; r++) {                                     \
                float m = fmaxf(fmaxf(rmax[0][rl + r], rmax[1][rl + r]),      \
                                fmaxf(rmax[2][rl + r], rmax[3][rl + r]));     \
                if (wc == 0 && l16 == 0) {                                    \
                    int row = rowBase + rl + r;                               \
                    if (row < M) QS[row] = m * (1.0f / 126.0f);               \
                }                                                             \
                float inv = m > 0.f ? 126.f / m : 0.f;                        \
                for (int j = 0; j < 4; j++)                                   \
                    sc[(rl + r) * 256 + wc * 64 + j * 16 + l16] =             \
                        (u8)((int)rintf(acc[i][j][r] * inv) + 128);           \
            }                                                                 \
        }                                                                     \
        __syncthreads();                                                      \
        for (int it = 0; it < 4; it++) {                                      \
            int id = it * 512 + tid;                                          \
            int row = id >> 4, c16 = (id & 15) * 16;                          \
            int grow = rowBase + row;                                         \
            if (grow < M)                                                     \
                *(uint4*)(Q8 + (size_t)grow * 256 + c16) =                    \
                    *(const uint4*)(sc + row * 256 + c16);                    \
        }                                                                     \
    }

#define GQ_LOAD_B                                                             \
    bf16x8 breg[4][8];                                                        \
    _Pragma("unroll")                                                         \
    for (int j = 0; j < 4; j++) {                                             \
        int col = wc * 64 + j * 16 + l16;                                     \
        _Pragma("unroll")                                                     \
        for (int ks = 0; ks < 8; ks++)                                        \
            breg[j][ks] =                                                     \
                *(const bf16x8*)(Bt + (size_t)col * 256 + ks * 32 + quad * 8);\
    }

__global__ __launch_bounds__(512, 2) void k_gemmq(const u16* __restrict__ A,
                                                  const u16* __restrict__ Bt,
                                                  u8* __restrict__ q8,
                                                  float* __restrict__ qs, int M) {
    __shared__ __align__(16) u8 sc[128 * 256];     // 32 KB byte stage
    __shared__ float rmax[4][128];                 // 2 KB rowmax partials
    const int tid = threadIdx.x;
    const int wave = tid >> 6, lane = tid & 63;
    const int wr = wave >> 2, wc = wave & 3;
    const int quad = lane >> 4, l16 = lane & 15;
    const int rowBase = blockIdx.x * 128;

    GQ_LOAD_B
    int arow[4];
#pragma unroll
    for (int i = 0; i < 4; i++) {
        int r = rowBase + wr * 64 + i * 16 + l16;
        arow[i] = (r < M) ? r : (M - 1);
    }
    f32x4 acc[4][4] = {};
#pragma unroll
    for (int ks = 0; ks < 8; ks++) {
        bf16x8 af[4];
#pragma unroll
        for (int i = 0; i < 4; i++)
            af[i] = *(const bf16x8*)(A + (size_t)arow[i] * 256 + ks * 32 +
                                     quad * 8);
#pragma unroll
        for (int i = 0; i < 4; i++)
#pragma unroll
            for (int j = 0; j < 4; j++)
                acc[i][j] = __builtin_amdgcn_mfma_f32_16x16x32_bf16(
                    af[i], breg[j][ks], acc[i][j], 0, 0, 0);
    }
    GQ_EPILOGUE(q8, qs)
}

// ---- GNN GEMM layer 0: A gathered from f32 emb + converted, fused quant ----
__global__ __launch_bounds__(512, 2) void k_gemm_embq(
        const int* __restrict__ tokens, const float* __restrict__ emb,
        const u16* __restrict__ Bt, u8* __restrict__ q8,
        float* __restrict__ qs, int M) {
    __shared__ __align__(16) u8 sc[128 * 256];
    __shared__ float rmax[4][128];
    const int tid = threadIdx.x;
    const int wave = tid >> 6, lane = tid & 63;
    const int wr = wave >> 2, wc = wave & 3;
    const int quad = lane >> 4, l16 = lane & 15;
    const int rowBase = blockIdx.x * 128;

    GQ_LOAD_B
    int tok[4];
#pragma unroll
    for (int i = 0; i < 4; i++) {
        int r = rowBase + wr * 64 + i * 16 + l16;
        tok[i] = tokens[(r < M) ? r : (M - 1)];
    }
    f32x4 acc[4][4] = {};
#pragma unroll
    for (int ks = 0; ks < 8; ks++) {
        bf16x8 af[4];
#pragma unroll
        for (int i = 0; i < 4; i++) {
            const float* sp = emb + (size_t)tok[i] * 256 + ks * 32 + quad * 8;
            float4 f0 = *(const float4*)sp;
            float4 f1 = *(const float4*)(sp + 4);
            uint4 pk;
            pk.x = pack2(f0.x, f0.y); pk.y = pack2(f0.z, f0.w);
            pk.z = pack2(f1.x, f1.y); pk.w = pack2(f1.z, f1.w);
            af[i] = *(bf16x8*)&pk;
        }
#pragma unroll
        for (int i = 0; i < 4; i++)
#pragma unroll
            for (int j = 0; j < 4; j++)
                acc[i][j] = __builtin_amdgcn_mfma_f32_16x16x32_bf16(
                    af[i], breg[j][ks], acc[i][j], 0, 0, 0);
    }
    GQ_EPILOGUE(q8, qs)
}

// ---- lin GEMM-1: A rows gathered from x via tgt (k_gather fused) ----
__global__ __launch_bounds__(256) void k_gemm_gather(const u16* __restrict__ X,
                                                     const int* __restrict__ tgt,
                                                     const u16* __restrict__ Bt,
                                                     u16* __restrict__ C, int M) {
    __shared__ __align__(16) u16 As[128 * 64];
    __shared__ __align__(16) u16 Bs[128 * 64];
    __shared__ int rowLDS[128];
    const int tid = threadIdx.x;
    const int wave = tid >> 6, lane = tid & 63;
    const int wm = wave >> 1, wn = wave & 1;
    const int rowBase = blockIdx.x * 128;
    const int colBase = blockIdx.y * 128;
    const int quad = lane >> 4, l16 = lane & 15;

    if (tid < 128) {
        int ga = rowBase + tid; if (ga >= M) ga = M - 1;
        rowLDS[tid] = tgt[ga];
    }
    f32x4 acc[4][4] = {};
    __syncthreads();

    for (int kk = 0; kk < 4; kk++) {
        int k0 = kk * 64;
#pragma unroll
        for (int i = 0; i < 4; i++) {
            int j = (i * 4 + wave) * 64 + lane;
            int r = j >> 3, c = j & 7;
            int cg = c ^ (r & 7);
            uint4 v = *(const uint4*)(X + (size_t)rowLDS[r] * 256 + k0 + cg * 8);
            *(uint4*)(&As[j * 8]) = v;
            gl2lds16(Bt + (size_t)(colBase + r) * 256 + k0 + cg * 8,
                     &Bs[(i * 4 + wave) * 512]);
        }
        __syncthreads();
        GEMM_COMPUTE(As, Bs)
        __syncthreads();
    }
    GEMM_EPILOGUE
}

// ---- fused aggregate + bias + LN + ReLU over int8 rows ----
// R2's proven lean shape: 8 dims/lane, fp16 weight in record,
// SINGLE per-row scale qs[s] (wave-uniform base -> broadcast load)
#define GF8(RR, Q0, Q1, Q2, Q3, W0, W1, W2, W3)                               \
    {                                                                         \
        int s0 = (int)(RR.x >> 15), s1 = (int)(RR.y >> 15);                   \
        int s2 = (int)(RR.z >> 15), s3 = (int)(RR.w >> 15);                   \
        Q0 = *(const uint2*)(qb + (size_t)s0 * 256);                          \
        Q1 = *(const uint2*)(qb + (size_t)s1 * 256);                          \
        Q2 = *(const uint2*)(qb + (size_t)s2 * 256);                          \
        Q3 = *(const uint2*)(qb + (size_t)s3 * 256);                          \
        W0 = recw(RR.x) * qs[s0]; W1 = recw(RR.y) * qs[s1];                   \
        W2 = recw(RR.z) * qs[s2]; W3 = recw(RR.w) * qs[s3];                   \
    }

#define GC8_ONE(Q, W)                                                         \
    {                                                                         \
        Ks += W;                                                              \
        a0 = fmaf(W, (float)(Q.x & 255u), a0);                                \
        a1 = fmaf(W, (float)((Q.x >> 8) & 255u), a1);                         \
        a2 = fmaf(W, (float)((Q.x >> 16) & 255u), a2);                        \
        a3 = fmaf(W, (float)(Q.x >> 24), a3);                                 \
        a4 = fmaf(W, (float)(Q.y & 255u), a4);                                \
        a5 = fmaf(W, (float)((Q.y >> 8) & 255u), a5);                         \
        a6 = fmaf(W, (float)((Q.y >> 16) & 255u), a6);                        \
        a7 = fmaf(W, (float)(Q.y >> 24), a7);                                 \
    }

__global__ __launch_bounds__(256) void k_aggr(const u8* __restrict__ q8,
                                              const float* __restrict__ qs,
                                              const int2* __restrict__ nodeInfo,
                                              const u32* __restrict__ csrp,
                                              const float* __restrict__ bias,
                                              const float* __restrict__ gamma,
                                              const float* __restrict__ beta,
                                              u16* __restrict__ xo) {
    const int wave = threadIdx.x >> 6, lane = threadIdx.x & 63;
    const int half = lane >> 5, l32 = lane & 31;
    const int node = blockIdx.x * 4 + wave;
    const int d8 = l32 * 8;                  // 8 dims per lane
    int2 ni = nodeInfo[node];
    float a0=0,a1=0,a2=0,a3=0,a4=0,a5=0,a6=0,a7=0;
    float Ks = 0.0f;
    const u8* qb = q8 + d8;
    const u32* cp = csrp + ni.x + half * 4;
    const int nrec = ni.y;
    int j = 0;
    for (; j + 16 <= nrec; j += 16, cp += 16) {
        uint4v ra = __builtin_nontemporal_load((const uint4v*)cp);
        uint4v rb = __builtin_nontemporal_load((const uint4v*)(cp + 8));
        uint2 qa0, qa1, qa2, qa3, qb0, qb1, qb2, qb3;
        float wa0, wa1, wa2, wa3, wb0, wb1, wb2, wb3;
        GF8(ra, qa0, qa1, qa2, qa3, wa0, wa1, wa2, wa3);
        GF8(rb, qb0, qb1, qb2, qb3, wb0, wb1, wb2, wb3);
        GC8_ONE(qa0, wa0); GC8_ONE(qa1, wa1);
        GC8_ONE(qa2, wa2); GC8_ONE(qa3, wa3);
        GC8_ONE(qb0, wb0); GC8_ONE(qb1, wb1);
        GC8_ONE(qb2, wb2); GC8_ONE(qb3, wb3);
    }
    if (j < nrec) {                          // nrec % 16 == 8 tail
        uint4v ra = __builtin_nontemporal_load((const uint4v*)cp);
        uint2 qa0, qa1, qa2, qa3;
        float wa0, wa1, wa2, wa3;
        GF8(ra, qa0, qa1, qa2, qa3, wa0, wa1, wa2, wa3);
        GC8_ONE(qa0, wa0); GC8_ONE(qa1, wa1);
        GC8_ONE(qa2, wa2); GC8_ONE(qa3, wa3);
    }
    a0 += __shfl_xor(a0, 32, 64); a1 += __shfl_xor(a1, 32, 64);
    a2 += __shfl_xor(a2, 32, 64); a3 += __shfl_xor(a3, 32, 64);
    a4 += __shfl_xor(a4, 32, 64); a5 += __shfl_xor(a5, 32, 64);
    a6 += __shfl_xor(a6, 32, 64); a7 += __shfl_xor(a7, 32, 64);
    Ks += __shfl_xor(Ks, 32, 64);
    float c128 = 128.0f * Ks;
    a0 -= c128; a1 -= c128; a2 -= c128; a3 -= c128;
    a4 -= c128; a5 -= c128; a6 -= c128; a7 -= c128;

    float4 b0 = *(const float4*)(bias + d8);
    float4 b1 = *(const float4*)(bias + d8 + 4);
    a0 += b0.x; a1 += b0.y; a2 += b0.z; a3 += b0.w;
    a4 += b1.x; a5 += b1.y; a6 += b1.z; a7 += b1.w;
    float s1 = a0+a1+a2+a3+a4+a5+a6+a7;
    float s2 = a0*a0+a1*a1+a2*a2+a3*a3+a4*a4+a5*a5+a6*a6+a7*a7;
    for (int o = 16; o >= 1; o >>= 1) {
        s1 += __shfl_xor(s1, o, 64);
        s2 += __shfl_xor(s2, o, 64);
    }
    float mean = s1 * (1.0f / 256.0f);
    float var = s2 * (1.0f / 256.0f) - mean * mean;
    float rstd = rsqrtf(var + 1e-5f);
    if (half == 0) {
        float4 g0 = *(const float4*)(gamma + d8);
        float4 g1 = *(const float4*)(gamma + d8 + 4);
        float4 e0 = *(const float4*)(beta + d8);
        float4 e1 = *(const float4*)(beta + d8 + 4);
        float y0 = fmaxf((a0 - mean) * rstd * g0.x + e0.x, 0.0f);
        float y1 = fmaxf((a1 - mean) * rstd * g0.y + e0.y, 0.0f);
        float y2 = fmaxf((a2 - mean) * rstd * g0.z + e0.z, 0.0f);
        float y3 = fmaxf((a3 - mean) * rstd * g0.w + e0.w, 0.0f);
        float y4 = fmaxf((a4 - mean) * rstd * g1.x + e1.x, 0.0f);
        float y5 = fmaxf((a5 - mean) * rstd * g1.y + e1.y, 0.0f);
        float y6 = fmaxf((a6 - mean) * rstd * g1.z + e1.z, 0.0f);
        float y7 = fmaxf((a7 - mean) * rstd * g1.w + e1.w, 0.0f);
        uint4v o;
        o.x = pack2(y0, y1);
        o.y = pack2(y2, y3);
        o.z = pack2(y4, y5);
        o.w = pack2(y6, y7);
        __builtin_nontemporal_store(o, (uint4v*)(xo + node * 256 + d8));
    }
}

__global__ __launch_bounds__(256) void k_lnrelu(const u16* __restrict__ h,
                                                const float* __restrict__ bias,
                                                const float* __restrict__ gamma,
                                                const float* __restrict__ beta,
                                                u16* __restrict__ xo) {
    int wave = threadIdx.x >> 6, lane = threadIdx.x & 63;
    int row = blockIdx.x * 4 + wave;
    int base = row * 256 + lane * 4;
    ushort4 hv = *(const ushort4*)(h + base);
    float4 bv = *(const float4*)(bias + lane * 4);
    float a0 = bf2f(hv.x) + bv.x, a1 = bf2f(hv.y) + bv.y;
    float a2 = bf2f(hv.z) + bv.z, a3 = bf2f(hv.w) + bv.w;
    float s1 = a0 + a1 + a2 + a3;
    float s2 = a0 * a0 + a1 * a1 + a2 * a2 + a3 * a3;
    for (int o = 32; o >= 1; o >>= 1) {
        s1 += __shfl_xor(s1, o, 64);
        s2 += __shfl_xor(s2, o, 64);
    }
    float mean = s1 * (1.0f / 256.0f);
    float var = s2 * (1.0f / 256.0f) - mean * mean;
    float rstd = rsqrtf(var + 1e-5f);
    float4 gv = *(const float4*)(gamma + lane * 4);
    float4 be = *(const float4*)(beta + lane * 4);
    float y0 = fmaxf((a0 - mean) * rstd * gv.x + be.x, 0.0f);
    float y1 = fmaxf((a1 - mean) * rstd * gv.y + be.y, 0.0f);
    float y2 = fmaxf((a2 - mean) * rstd * gv.z + be.z, 0.0f);
    float y3 = fmaxf((a3 - mean) * rstd * gv.w + be.w, 0.0f);
    ushort4 o4;
    o4.x = f2bf(y0); o4.y = f2bf(y1); o4.z = f2bf(y2); o4.w = f2bf(y3);
    *(ushort4*)(xo + base) = o4;
}

// ---- last layer: bias + LN + ReLU + [256x10] out-proj fused ----
__global__ __launch_bounds__(256) void k_lnout(const u16* __restrict__ h,
                                               const float* __restrict__ bias,
                                               const float* __restrict__ gamma,
                                               const float* __restrict__ beta,
                                               const float* __restrict__ W,
                                               const float* __restrict__ ob,
                                               float* __restrict__ out) {
    __shared__ float Ws[DD * NOUT];
    int tid = threadIdx.x;
    for (int i = tid; i < DD * NOUT; i += 256) Ws[i] = W[i];
    __syncthreads();
    int wave = tid >> 6, lane = tid & 63;
    int row = blockIdx.x * 4 + wave;
    int base = row * 256 + lane * 4;
    ushort4 hv = *(const ushort4*)(h + base);
    float4 bv = *(const float4*)(bias + lane * 4);
    float a0 = bf2f(hv.x) + bv.x, a1 = bf2f(hv.y) + bv.y;
    float a2 = bf2f(hv.z) + bv.z, a3 = bf2f(hv.w) + bv.w;
    float s1 = a0 + a1 + a2 + a3;
    float s2 = a0 * a0 + a1 * a1 + a2 * a2 + a3 * a3;
    for (int o = 32; o >= 1; o >>= 1) {
        s1 += __shfl_xor(s1, o, 64);
        s2 += __shfl_xor(s2, o, 64);
    }
    float mean = s1 * (1.0f / 256.0f);
    float var = s2 * (1.0f / 256.0f) - mean * mean;
    float rstd = rsqrtf(var + 1e-5f);
    float4 gv = *(const float4*)(gamma + lane * 4);
    float4 be = *(const float4*)(beta + lane * 4);
    // match reference numerics: y = bf16(relu(...)) then matmul
    float y0 = bf2f(f2bf(fmaxf((a0 - mean) * rstd * gv.x + be.x, 0.0f)));
    float y1 = bf2f(f2bf(fmaxf((a1 - mean) * rstd * gv.y + be.y, 0.0f)));
    float y2 = bf2f(f2bf(fmaxf((a2 - mean) * rstd * gv.z + be.z, 0.0f)));
    float y3 = bf2f(f2bf(fmaxf((a3 - mean) * rstd * gv.w + be.w, 0.0f)));
    int d = lane * 4;
    for (int o = 0; o < NOUT; o++) {
        float p = y0 * Ws[(d + 0) * NOUT + o] + y1 * Ws[(d + 1) * NOUT + o] +
                  y2 * Ws[(d + 2) * NOUT + o] + y3 * Ws[(d + 3) * NOUT + o];
        for (int off = 32; off >= 1; off >>= 1) p += __shfl_xor(p, off, 64);
        if (lane == 0) out[row * NOUT + o] = p + ob[o];
    }
}

extern "C" void kernel_launch(void* const* d_in, const int* in_sizes, int n_in,
                              void* d_out, int out_size, void* d_ws, size_t ws_size,
                              hipStream_t stream) {
    (void)in_sizes; (void)n_in; (void)out_size; (void)ws_size;
    const int* tokens = (const int*)d_in[0];
    const int* edges = (const int*)d_in[1];
    const int* tgt = (const int*)d_in[2];
    const float* emb = (const float*)d_in[3];
    const float* gnn_W = (const float*)d_in[4];
    const float* gnn_b = (const float*)d_in[5];
    const float* gnn_g = (const float*)d_in[6];
    const float* gnn_be = (const float*)d_in[7];
    const float* lin_W = (const float*)d_in[8];
    const float* lin_b = (const float*)d_in[9];
    const float* lin_g = (const float*)d_in[10];
    const float* lin_be = (const float*)d_in[11];
    const float* out_W = (const float*)d_in[12];
    const float* out_b = (const float*)d_in[13];
    float* out = (float*)d_out;

    char* ws = (char*)d_ws;
    u16* x = (u16*)ws;           ws += (size_t)NN * 256 * 2;
    // recs region (dead after csr build)
    char* hreg = ws;             ws += (size_t)NN * 256 * 2;
    int* recs = (int*)hreg;      // NE*4 = 12.8MB < 51.2MB
    u32* csrp = (u32*)ws;        ws += (size_t)CSRP_CAP * 4;
    int2* nodeInfo = (int2*)ws;  ws += (size_t)NN * 8;
    float* dinv = (float*)ws;    ws += (size_t)NN * 4;
    int* bucketCnt = (int*)ws;   ws += 256 * 4;
    int* bucketOff = (int*)ws;   ws += 256 * 4;
    int* bucketCur = (int*)ws;   ws += 256 * 4;
    u16* Wt = (u16*)ws;          ws += (size_t)6 * 65536 * 2;
    u16* xt = (u16*)ws;          ws += (size_t)NT * 256 * 2;
    u16* ht = (u16*)ws;          ws += (size_t)NT * 256 * 2;
    u8* q8 = (u8*)ws;            ws += (size_t)(NN + 128) * 256;
    float* qs = (float*)ws;      ws += (size_t)(NN + 128) * 4;  // [NN]

    const int* e_src = edges;
    const int* e_dst = edges + NE;

    k_wt<<<1536, 256, 0, stream>>>(gnn_W, lin_W, Wt, bucketCnt);
    k_binA<<<782, 256, 0, stream>>>(e_dst, bucketCnt);
    k_bscan<<<1, 256, 0, stream>>>(bucketCnt, bucketOff, bucketCur);
    k_binB<<<196, 1024, 0, stream>>>(e_src, e_dst, bucketCur, recs);
    k_csrA<<<NBUCK, 256, 0, stream>>>(recs, bucketOff, nodeInfo, dinv, csrp);
    k_csrB<<<NBUCK, 256, 0, stream>>>(recs, bucketOff, nodeInfo, dinv, csrp);

    for (int l = 0; l < 4; l++) {
        if (l == 0)
            k_gemm_embq<<<782, 512, 0, stream>>>(tokens, emb, Wt,
                                                 q8, qs, NN);
        else
            k_gemmq<<<782, 512, 0, stream>>>(x, Wt + l * 65536,
                                             q8, qs, NN);
        k_aggr<<<25000, 256, 0, stream>>>(q8, qs, nodeInfo, csrp,
                                          gnn_b + l * 256, gnn_g + l * 256,
                                          gnn_be + l * 256, x);
    }
    // lin layer 0: gather fused into GEMM A-staging
    k_gemm_gather<<<dim3(64, 2), 256, 0, stream>>>(x, tgt, Wt + 4 * 65536,
                                                   ht, NT);
    k_lnrelu<<<2048, 256, 0, stream>>>(ht, lin_b, lin_g, lin_be, xt);
    // lin layer 1: GEMM then LN+ReLU+out-proj fused
    k_gemm<<<dim3(64, 2), 256, 0, stream>>>(xt, Wt + 5 * 65536, ht, NT);
    k_lnout<<<2048, 256, 0, stream>>>(ht, lin_b + 256, lin_g + 256,
                                      lin_be + 256, out_W, out_b, out);
}

// Round 8
// 955.025 us; speedup vs baseline: 1.1887x; 1.1887x over previous
//
#include <hip/hip_runtime.h>
#include <hip/hip_fp16.h>

#define NN 100000
#define NE 3200000
#define DD 256
#define NT 8192
#define NOUT 10
#define NBUCK 196        // ceil(100000/512) buckets of 512 dst nodes
// per bucket: edges + 512 self + <=512*7 pad + 8 align slack
#define CSRP_CAP (NE + NBUCK * 4112 + 64)

typedef unsigned short u16;
typedef unsigned int u32;
typedef unsigned char u8;
typedef __attribute__((ext_vector_type(8))) short bf16x8;
typedef __attribute__((ext_vector_type(4))) float f32x4;
typedef __attribute__((ext_vector_type(4))) unsigned int uint4v;

__device__ __forceinline__ float bf2f(u16 u) {
    union { unsigned int i; float f; } v; v.i = ((unsigned int)u) << 16; return v.f;
}
__device__ __forceinline__ u16 f2bf(float f) {
    union { float f; unsigned int i; } v; v.f = f;
    unsigned int x = v.i;
    return (u16)((x + 0x7fffu + ((x >> 16) & 1u)) >> 16);
}
__device__ __forceinline__ unsigned int pack2(float a, float b) {
    return (unsigned int)f2bf(a) | ((unsigned int)f2bf(b) << 16);
}
// pack src(17b) | fp16-no-sign(15b); w>0 always
__device__ __forceinline__ u32 packrec(int src, float w) {
    unsigned short h = __half_as_ushort(__float2half(w));
    return ((u32)src << 15) | (u32)(h & 0x7fff);
}
__device__ __forceinline__ float recw(u32 r) {
    return __half2float(__ushort_as_half((unsigned short)(r & 0x7fff)));
}

__device__ __forceinline__ void gl2lds16(const void* g, void* l) {
    __builtin_amdgcn_global_load_lds(
        (const __attribute__((address_space(1))) unsigned int*)g,
        (__attribute__((address_space(3))) unsigned int*)l, 16, 0, 0);
}

// ---- weight convert + transpose: Wt[l][n][k] = bf16(W[l][k][n]) ----
// block 0 also zeroes bucketCnt (saves a dispatch)
__global__ __launch_bounds__(256) void k_wt(const float* __restrict__ gW,
                                            const float* __restrict__ lW,
                                            u16* __restrict__ Wt,
                                            int* __restrict__ bucketCnt) {
    if (blockIdx.x == 0 && threadIdx.x < NBUCK) bucketCnt[threadIdx.x] = 0;
    int idx = blockIdx.x * 256 + threadIdx.x;      // < 6*65536
    int l = idx >> 16;
    int nk = idx & 65535;
    int n = nk >> 8, k = nk & 255;
    float v = (l < 4) ? gW[l * 65536 + k * 256 + n]
                      : lW[(l - 4) * 65536 + k * 256 + n];
    Wt[idx] = f2bf(v);
}

// ---- pass A: per-bucket edge counts ----
__global__ __launch_bounds__(256) void k_binA(const int* __restrict__ dst,
                                              int* __restrict__ bucketCnt) {
    __shared__ int hist[NBUCK];
    int t = threadIdx.x;
    if (t < NBUCK) hist[t] = 0;
    __syncthreads();
    int base = blockIdx.x * 4096;
#pragma unroll
    for (int i = 0; i < 16; i++) {
        int e = base + i * 256 + t;
        if (e < NE) atomicAdd(&hist[dst[e] >> 9], 1);
    }
    __syncthreads();
    if (t < NBUCK && hist[t] > 0) atomicAdd(&bucketCnt[t], hist[t]);
}

// ---- scan bucket counts -> bucketOff (stable) + bucketCur (cursor) ----
__global__ __launch_bounds__(256) void k_bscan(const int* __restrict__ bucketCnt,
                                               int* __restrict__ bucketOff,
                                               int* __restrict__ bucketCur) {
    __shared__ int s[256];
    int t = threadIdx.x;
    int v = (t < NBUCK) ? bucketCnt[t] : 0;
    s[t] = v;
    __syncthreads();
    for (int o = 1; o < 256; o <<= 1) {
        int a = (t >= o) ? s[t - o] : 0;
        __syncthreads();
        s[t] += a;
        __syncthreads();
    }
    if (t < NBUCK) {
        int ex = s[t] - v;
        bucketOff[t] = ex;
        bucketCur[t] = ex;
    }
    if (t == 0) bucketOff[NBUCK] = NE;
}

// ---- pass B: write records at ABSOLUTE bucket offsets ----
// record = (src << 9) | (dst & 511)   (src < 2^17)
__global__ __launch_bounds__(1024) void k_binB(const int* __restrict__ src,
                                               const int* __restrict__ dst,
                                               int* __restrict__ bucketCur,
                                               int* __restrict__ recs) {
    __shared__ int hist[NBUCK];
    __shared__ int gbase[NBUCK];
    int t = threadIdx.x;
    if (t < NBUCK) hist[t] = 0;
    __syncthreads();
    int base = blockIdx.x * 16384;
    int recv[16], bks[16], rnk[16];
#pragma unroll
    for (int i = 0; i < 16; i++) {
        int e = base + i * 1024 + t;
        int bk = -1, rec = 0;
        if (e < NE) {
            int s_ = src[e], d_ = dst[e];
            bk = d_ >> 9;
            rec = (s_ << 9) | (d_ & 511);
        }
        bks[i] = bk; recv[i] = rec;
    }
#pragma unroll
    for (int i = 0; i < 16; i++)
        rnk[i] = (bks[i] >= 0) ? atomicAdd(&hist[bks[i]], 1) : 0;
    __syncthreads();
    if (t < NBUCK) {
        int c = hist[t];
        gbase[t] = (c > 0) ? atomicAdd(&bucketCur[t], c) : 0;  // absolute
    }
    __syncthreads();
#pragma unroll
    for (int i = 0; i < 16; i++)
        if (bks[i] >= 0) {
            int pos = gbase[bks[i]] + rnk[i];
            pos = min(max(pos, 0), NE - 1);
            recs[pos] = recv[i];
        }
}

// ---- csrA: per-bucket count + padded scan -> nodeInfo/dinv/self/dummies ----
// csrp record = u32 (src<<15)|fp16w; per node: [self][edges...][dummies] pad 8
// NOTE: must be a SEPARATE dispatch from csrB — csrB reads dinv[s] for
// arbitrary s (cross-bucket); merging creates a cross-workgroup RAW race (R9).
__global__ __launch_bounds__(256) void k_csrA(const int* __restrict__ recs,
                                              const int* __restrict__ bucketOff,
                                              int2* __restrict__ nodeInfo,
                                              float* __restrict__ dinv,
                                              u32* __restrict__ csrp) {
    __shared__ int cnt[512], off[512];
    int b = blockIdx.x, t = threadIdx.x;
    int beg = min(max(bucketOff[b], 0), NE);
    int end = min(max(bucketOff[b + 1], beg), NE);
    int n = end - beg;
    cnt[t] = 0; cnt[t + 256] = 0;
    __syncthreads();
    for (int i = t; i < n; i += 256)
        atomicAdd(&cnt[recs[beg + i] & 511], 1);
    __syncthreads();
    off[t] = (cnt[t] + 8) & ~7;            // padded size: cnt+1 self, round to 8
    off[t + 256] = (cnt[t + 256] + 8) & ~7;
    __syncthreads();
    for (int o = 1; o < 512; o <<= 1) {
        int v0 = (t >= o) ? off[t - o] : 0;
        int v1 = (t + 256 >= o) ? off[t + 256 - o] : 0;
        __syncthreads();
        off[t] += v0; off[t + 256] += v1;
        __syncthreads();
    }
    int base = (beg + b * 4112 + 7) & ~7;  // 8-record aligned bucket region
    for (int k = t; k < 512; k += 256) {
        int node = b * 512 + k;
        if (node >= NN) continue;
        int pd = (cnt[k] + 8) & ~7;
        int nbeg = base + off[k] - pd;     // exclusive padded scan (8-aligned)
        int2 ni; ni.x = nbeg; ni.y = pd;
        nodeInfo[node] = ni;
        float di = rsqrtf((float)(cnt[k] + 1));
        dinv[node] = di;
        csrp[nbeg] = packrec(node, di * di);
        for (int j = nbeg + 1 + cnt[k]; j < nbeg + pd; j++) csrp[j] = 0u;
    }
}

// ---- csrB: scatter edges with precomputed fp16 weight ----
__global__ __launch_bounds__(256) void k_csrB(const int* __restrict__ recs,
                                              const int* __restrict__ bucketOff,
                                              const int2* __restrict__ nodeInfo,
                                              const float* __restrict__ dinv,
                                              u32* __restrict__ csrp) {
    __shared__ int cur[512];
    int b = blockIdx.x, t = threadIdx.x;
    cur[t] = 0; cur[t + 256] = 0;
    __syncthreads();
    int beg = min(max(bucketOff[b], 0), NE);
    int end = min(max(bucketOff[b + 1], beg), NE);
    int n = end - beg;
    for (int i = t; i < n; i += 256) {
        int r = recs[beg + i];
        int dlow = r & 511;
        int s = min(max(r >> 9, 0), NN - 1);
        int node = b * 512 + dlow;
        int rk = atomicAdd(&cur[dlow], 1);
        int2 ni = nodeInfo[node];
        float w = dinv[s] * dinv[node];
        int pos = ni.x + 1 + rk;
        pos = min(max(pos, 0), CSRP_CAP - 1);
        csrp[pos] = packrec(s, w);
    }
}

// ---- shared GEMM epilogue (bf16 C) — lin-layer 128x128 kernels ----
#define GEMM_EPILOGUE                                                         \
    for (int i = 0; i < 4; i++)                                               \
        for (int j = 0; j < 4; j++) {                                         \
            int col = colBase + wn * 64 + j * 16 + l16;                       \
            for (int r = 0; r < 4; r++) {                                     \
                int row = rowBase + wm * 64 + i * 16 + quad * 4 + r;          \
                if (row < M) C[row * 256 + col] = f2bf(acc[i][j][r]);         \
            }                                                                 \
        }

#define GEMM_COMPUTE(ASRC, BSRC)                                              \
    for (int ks = 0; ks < 2; ks++) {                                          \
        bf16x8 a_frag[4], b_frag[4];                                          \
        for (int i = 0; i < 4; i++) {                                         \
            int r = wm * 64 + i * 16 + l16;                                   \
            int ch = (ks * 4 + quad) ^ (r & 7);                               \
            a_frag[i] = *(const bf16x8*)(&ASRC[r * 64 + ch * 8]);             \
        }                                                                     \
        for (int j = 0; j < 4; j++) {                                         \
            int r = wn * 64 + j * 16 + l16;                                   \
            int ch = (ks * 4 + quad) ^ (r & 7);                               \
            b_frag[j] = *(const bf16x8*)(&BSRC[r * 64 + ch * 8]);             \
        }                                                                     \
        for (int i = 0; i < 4; i++)                                           \
            for (int j = 0; j < 4; j++)                                       \
                acc[i][j] = __builtin_amdgcn_mfma_f32_16x16x32_bf16(          \
                    a_frag[i], b_frag[j], acc[i][j], 0, 0, 0);                \
    }

// ---- GNN GEMM compute for 64x256 tile (wm=0, wn=wave 0..3) ----
#define GEMMQ_COMPUTE                                                         \
    for (int ks = 0; ks < 2; ks++) {                                          \
        bf16x8 a_frag[4], b_frag[4];                                          \
        for (int i = 0; i < 4; i++) {                                         \
            int r = i * 16 + l16;                                             \
            int ch = (ks * 4 + quad) ^ (r & 7);                               \
            a_frag[i] = *(const bf16x8*)(&As[r * 64 + ch * 8]);               \
        }                                                                     \
        for (int j = 0; j < 4; j++) {                                         \
            int r = wn * 64 + j * 16 + l16;                                   \
            int ch = (ks * 4 + quad) ^ (r & 7);                               \
            b_frag[j] = *(const bf16x8*)(&Bs[r * 64 + ch * 8]);               \
        }                                                                     \
        for (int i = 0; i < 4; i++)                                           \
            for (int j = 0; j < 4; j++)                                       \
                acc[i][j] = __builtin_amdgcn_mfma_f32_16x16x32_bf16(          \
                    a_frag[i], b_frag[j], acc[i][j], 0, 0, 0);                \
    }

// ---- quant epilogue for 64x256 tile: SINGLE per-row scale (full 256 cols) ->
// int8 bytes + qs[NN]. rowmax through As (dead), bytes through Bs (dead). ----
#define QUANTQ_EPILOGUE(Q8, QS)                                               \
    {                                                                         \
        float* rowmaxLDS = (float*)As;        /* [4][64] */                   \
        for (int i = 0; i < 4; i++)                                           \
            for (int r = 0; r < 4; r++) {                                     \
                float m = 0.f;                                                \
                for (int j = 0; j < 4; j++)                                   \
                    m = fmaxf(m, fabsf(acc[i][j][r]));                        \
                m = fmaxf(m, __shfl_xor(m, 1, 64));                           \
                m = fmaxf(m, __shfl_xor(m, 2, 64));                           \
                m = fmaxf(m, __shfl_xor(m, 4, 64));                           \
                m = fmaxf(m, __shfl_xor(m, 8, 64));                           \
                if (l16 == 0)                                                 \
                    rowmaxLDS[wn * 64 + i * 16 + quad * 4 + r] = m;           \
            }                                                                 \
        __syncthreads();                                                      \
        u8* bb = (u8*)Bs;                      /* [64][256] */                \
        for (int i = 0; i < 4; i++)                                           \
            for (int r = 0; r < 4; r++) {                                     \
                int rl = i * 16 + quad * 4 + r;                               \
                float m = fmaxf(fmaxf(rowmaxLDS[rl], rowmaxLDS[64 + rl]),     \
                                fmaxf(rowmaxLDS[128 + rl],                    \
                                      rowmaxLDS[192 + rl]));                  \
                if (wn == 0 && l16 == 0) {                                    \
                    int row = rowBase + rl;                                   \
                    if (row < M) QS[row] = m * (1.0f / 126.0f);               \
                }                                                             \
                float inv = m > 0.f ? 126.f / m : 0.f;                        \
                for (int j = 0; j < 4; j++)                                   \
                    bb[rl * 256 + wn * 64 + j * 16 + l16] =                   \
                        (u8)((int)rintf(acc[i][j][r] * inv) + 128);           \
            }                                                                 \
        __syncthreads();                                                      \
        for (int u = 0; u < 4; u++) {                                         \
            int v = u * 256 + tid;                                            \
            int rl = v >> 4, c16 = (v & 15) * 16;                             \
            int row = rowBase + rl;                                           \
            if (row < M)                                                      \
                *(uint4*)(Q8 + (size_t)row * 256 + c16) =                     \
                    *(const uint4*)(bb + rl * 256 + c16);                     \
        }                                                                     \
    }

// ---- bf16 MFMA GEMM (bf16 C out) — lin layers, 128x128 tile ----
__global__ __launch_bounds__(256) void k_gemm(const u16* __restrict__ A,
                                              const u16* __restrict__ Bt,
                                              u16* __restrict__ C, int M) {
    __shared__ __align__(16) u16 As[128 * 64];
    __shared__ __align__(16) u16 Bs[128 * 64];
    const int tid = threadIdx.x;
    const int wave = tid >> 6, lane = tid & 63;
    const int wm = wave >> 1, wn = wave & 1;
    const int rowBase = blockIdx.x * 128;
    const int colBase = blockIdx.y * 128;
    const int quad = lane >> 4, l16 = lane & 15;

    f32x4 acc[4][4] = {};

    for (int kk = 0; kk < 4; kk++) {
        int k0 = kk * 64;
#pragma unroll
        for (int i = 0; i < 4; i++) {
            int j = (i * 4 + wave) * 64 + lane;    // task 0..1023
            int r = j >> 3, c = j & 7;
            int cg = c ^ (r & 7);                  // source-chunk swizzle
            int ga = rowBase + r; if (ga >= M) ga = M - 1;
            gl2lds16(A + (size_t)ga * 256 + k0 + cg * 8,
                     &As[(i * 4 + wave) * 512]);
            gl2lds16(Bt + (size_t)(colBase + r) * 256 + k0 + cg * 8,
                     &Bs[(i * 4 + wave) * 512]);
        }
        __syncthreads();
        GEMM_COMPUTE(As, Bs)
        __syncthreads();
    }
    GEMM_EPILOGUE
}

// ---- GNN GEMM: 64x256 tile, bf16 A x Bt, fused int8-quant (1 scale/row) ----
__global__ __launch_bounds__(256) void k_gemmq(const u16* __restrict__ A,
                                               const u16* __restrict__ Bt,
                                               u8* __restrict__ q8,
                                               float* __restrict__ qs, int M) {
    __shared__ __align__(16) u16 As[64 * 64];
    __shared__ __align__(16) u16 Bs[256 * 64];
    const int tid = threadIdx.x;
    const int wave = tid >> 6, lane = tid & 63;
    const int wn = wave;
    const int rowBase = blockIdx.x * 64;
    const int quad = lane >> 4, l16 = lane & 15;

    f32x4 acc[4][4] = {};

    for (int kk = 0; kk < 4; kk++) {
        int k0 = kk * 64;
#pragma unroll
        for (int i = 0; i < 2; i++) {              // A: 64 rows x 64 k
            int j = (i * 4 + wave) * 64 + lane;    // task 0..511
            int r = j >> 3, c = j & 7;
            int cg = c ^ (r & 7);
            int ga = rowBase + r; if (ga >= M) ga = M - 1;
            gl2lds16(A + (size_t)ga * 256 + k0 + cg * 8,
                     &As[(i * 4 + wave) * 512]);
        }
#pragma unroll
        for (int i = 0; i < 8; i++) {              // B: 256 n x 64 k
            int j = (i * 4 + wave) * 64 + lane;    // task 0..2047
            int r = j >> 3, c = j & 7;
            int cg = c ^ (r & 7);
            gl2lds16(Bt + (size_t)r * 256 + k0 + cg * 8,
                     &Bs[(i * 4 + wave) * 512]);
        }
        __syncthreads();
        GEMMQ_COMPUTE
        __syncthreads();
    }
    QUANTQ_EPILOGUE(q8, qs)
}

// ---- GNN GEMM layer 0: 64x256 tile, A gathered from f32 emb, fused quant ----
__global__ __launch_bounds__(256) void k_gemm_embq(const int* __restrict__ tokens,
                                                   const float* __restrict__ emb,
                                                   const u16* __restrict__ Bt,
                                                   u8* __restrict__ q8,
                                                   float* __restrict__ qs, int M) {
    __shared__ __align__(16) u16 As[64 * 64];
    __shared__ __align__(16) u16 Bs[256 * 64];
    __shared__ int tokLDS[64];
    const int tid = threadIdx.x;
    const int wave = tid >> 6, lane = tid & 63;
    const int wn = wave;
    const int rowBase = blockIdx.x * 64;
    const int quad = lane >> 4, l16 = lane & 15;

    if (tid < 64) {
        int ga = rowBase + tid; if (ga >= M) ga = M - 1;
        tokLDS[tid] = tokens[ga];
    }
    f32x4 acc[4][4] = {};
    __syncthreads();

    for (int kk = 0; kk < 4; kk++) {
        int k0 = kk * 64;
#pragma unroll
        for (int i = 0; i < 2; i++) {              // A: gather f32 emb rows
            int j = (i * 4 + wave) * 64 + lane;    // task 0..511
            int r = j >> 3, c = j & 7;
            int cg = c ^ (r & 7);
            const float* srcp = emb + (size_t)tokLDS[r] * 256 + k0 + cg * 8;
            float4 f0 = *(const float4*)srcp;
            float4 f1 = *(const float4*)(srcp + 4);
            uint4 pk;
            pk.x = pack2(f0.x, f0.y); pk.y = pack2(f0.z, f0.w);
            pk.z = pack2(f1.x, f1.y); pk.w = pack2(f1.z, f1.w);
            *(uint4*)(&As[j * 8]) = pk;
        }
#pragma unroll
        for (int i = 0; i < 8; i++) {              // B: 256 n x 64 k
            int j = (i * 4 + wave) * 64 + lane;
            int r = j >> 3, c = j & 7;
            int cg = c ^ (r & 7);
            gl2lds16(Bt + (size_t)r * 256 + k0 + cg * 8,
                     &Bs[(i * 4 + wave) * 512]);
        }
        __syncthreads();
        GEMMQ_COMPUTE
        __syncthreads();
    }
    QUANTQ_EPILOGUE(q8, qs)
}

// ---- lin GEMM-1: A rows gathered from x via tgt (k_gather fused) ----
__global__ __launch_bounds__(256) void k_gemm_gather(const u16* __restrict__ X,
                                                     const int* __restrict__ tgt,
                                                     const u16* __restrict__ Bt,
                                                     u16* __restrict__ C, int M) {
    __shared__ __align__(16) u16 As[128 * 64];
    __shared__ __align__(16) u16 Bs[128 * 64];
    __shared__ int rowLDS[128];
    const int tid = threadIdx.x;
    const int wave = tid >> 6, lane = tid & 63;
    const int wm = wave >> 1, wn = wave & 1;
    const int rowBase = blockIdx.x * 128;
    const int colBase = blockIdx.y * 128;
    const int quad = lane >> 4, l16 = lane & 15;

    if (tid < 128) {
        int ga = rowBase + tid; if (ga >= M) ga = M - 1;
        rowLDS[tid] = tgt[ga];
    }
    f32x4 acc[4][4] = {};
    __syncthreads();

    for (int kk = 0; kk < 4; kk++) {
        int k0 = kk * 64;
#pragma unroll
        for (int i = 0; i < 4; i++) {
            int j = (i * 4 + wave) * 64 + lane;
            int r = j >> 3, c = j & 7;
            int cg = c ^ (r & 7);
            uint4 v = *(const uint4*)(X + (size_t)rowLDS[r] * 256 + k0 + cg * 8);
            *(uint4*)(&As[j * 8]) = v;
            gl2lds16(Bt + (size_t)(colBase + r) * 256 + k0 + cg * 8,
                     &Bs[(i * 4 + wave) * 512]);
        }
        __syncthreads();
        GEMM_COMPUTE(As, Bs)
        __syncthreads();
    }
    GEMM_EPILOGUE
}

// ---- fused aggregate + bias + LN + ReLU over int8 rows ----
// R2's proven lean shape: 8 dims/lane, fp16 weight in record,
// SINGLE per-row scale qs[s] (wave-uniform base -> broadcast load)
#define GF8(RR, Q0, Q1, Q2, Q3, W0, W1, W2, W3)                               \
    {                                                                         \
        int s0 = (int)(RR.x >> 15), s1 = (int)(RR.y >> 15);                   \
        int s2 = (int)(RR.z >> 15), s3 = (int)(RR.w >> 15);                   \
        Q0 = *(const uint2*)(qb + (size_t)s0 * 256);                          \
        Q1 = *(const uint2*)(qb + (size_t)s1 * 256);                          \
        Q2 = *(const uint2*)(qb + (size_t)s2 * 256);                          \
        Q3 = *(const uint2*)(qb + (size_t)s3 * 256);                          \
        W0 = recw(RR.x) * qs[s0]; W1 = recw(RR.y) * qs[s1];                   \
        W2 = recw(RR.z) * qs[s2]; W3 = recw(RR.w) * qs[s3];                   \
    }

#define GC8_ONE(Q, W)                                                         \
    {                                                                         \
        Ks += W;                                                              \
        a0 = fmaf(W, (float)(Q.x & 255u), a0);                                \
        a1 = fmaf(W, (float)((Q.x >> 8) & 255u), a1);                         \
        a2 = fmaf(W, (float)((Q.x >> 16) & 255u), a2);                        \
        a3 = fmaf(W, (float)(Q.x >> 24), a3);                                 \
        a4 = fmaf(W, (float)(Q.y & 255u), a4);                                \
        a5 = fmaf(W, (float)((Q.y >> 8) & 255u), a5);                         \
        a6 = fmaf(W, (float)((Q.y >> 16) & 255u), a6);                        \
        a7 = fmaf(W, (float)(Q.y >> 24), a7);                                 \
    }

__global__ __launch_bounds__(256) void k_aggr(const u8* __restrict__ q8,
                                              const float* __restrict__ qs,
                                              const int2* __restrict__ nodeInfo,
                                              const u32* __restrict__ csrp,
                                              const float* __restrict__ bias,
                                              const float* __restrict__ gamma,
                                              const float* __restrict__ beta,
                                              u16* __restrict__ xo) {
    const int wave = threadIdx.x >> 6, lane = threadIdx.x & 63;
    const int half = lane >> 5, l32 = lane & 31;
    const int node = blockIdx.x * 4 + wave;
    const int d8 = l32 * 8;                  // 8 dims per lane
    int2 ni = nodeInfo[node];
    float a0=0,a1=0,a2=0,a3=0,a4=0,a5=0,a6=0,a7=0;
    float Ks = 0.0f;
    const u8* qb = q8 + d8;
    const u32* cp = csrp + ni.x + half * 4;
    const int nrec = ni.y;
    int j = 0;
    for (; j + 16 <= nrec; j += 16, cp += 16) {
        uint4v ra = __builtin_nontemporal_load((const uint4v*)cp);
        uint4v rb = __builtin_nontemporal_load((const uint4v*)(cp + 8));
        uint2 qa0, qa1, qa2, qa3, qb0, qb1, qb2, qb3;
        float wa0, wa1, wa2, wa3, wb0, wb1, wb2, wb3;
        GF8(ra, qa0, qa1, qa2, qa3, wa0, wa1, wa2, wa3);
        GF8(rb, qb0, qb1, qb2, qb3, wb0, wb1, wb2, wb3);
        GC8_ONE(qa0, wa0); GC8_ONE(qa1, wa1);
        GC8_ONE(qa2, wa2); GC8_ONE(qa3, wa3);
        GC8_ONE(qb0, wb0); GC8_ONE(qb1, wb1);
        GC8_ONE(qb2, wb2); GC8_ONE(qb3, wb3);
    }
    if (j < nrec) {                          // nrec % 16 == 8 tail
        uint4v ra = __builtin_nontemporal_load((const uint4v*)cp);
        uint2 qa0, qa1, qa2, qa3;
        float wa0, wa1, wa2, wa3;
        GF8(ra, qa0, qa1, qa2, qa3, wa0, wa1, wa2, wa3);
        GC8_ONE(qa0, wa0); GC8_ONE(qa1, wa1);
        GC8_ONE(qa2, wa2); GC8_ONE(qa3, wa3);
    }
    a0 += __shfl_xor(a0, 32, 64); a1 += __shfl_xor(a1, 32, 64);
    a2 += __shfl_xor(a2, 32, 64); a3 += __shfl_xor(a3, 32, 64);
    a4 += __shfl_xor(a4, 32, 64); a5 += __shfl_xor(a5, 32, 64);
    a6 += __shfl_xor(a6, 32, 64); a7 += __shfl_xor(a7, 32, 64);
    Ks += __shfl_xor(Ks, 32, 64);
    float c128 = 128.0f * Ks;
    a0 -= c128; a1 -= c128; a2 -= c128; a3 -= c128;
    a4 -= c128; a5 -= c128; a6 -= c128; a7 -= c128;

    float4 b0 = *(const float4*)(bias + d8);
    float4 b1 = *(const float4*)(bias + d8 + 4);
    a0 += b0.x; a1 += b0.y; a2 += b0.z; a3 += b0.w;
    a4 += b1.x; a5 += b1.y; a6 += b1.z; a7 += b1.w;
    float s1 = a0+a1+a2+a3+a4+a5+a6+a7;
    float s2 = a0*a0+a1*a1+a2*a2+a3*a3+a4*a4+a5*a5+a6*a6+a7*a7;
    for (int o = 16; o >= 1; o >>= 1) {
        s1 += __shfl_xor(s1, o, 64);
        s2 += __shfl_xor(s2, o, 64);
    }
    float mean = s1 * (1.0f / 256.0f);
    float var = s2 * (1.0f / 256.0f) - mean * mean;
    float rstd = rsqrtf(var + 1e-5f);
    if (half == 0) {
        float4 g0 = *(const float4*)(gamma + d8);
        float4 g1 = *(const float4*)(gamma + d8 + 4);
        float4 e0 = *(const float4*)(beta + d8);
        float4 e1 = *(const float4*)(beta + d8 + 4);
        float y0 = fmaxf((a0 - mean) * rstd * g0.x + e0.x, 0.0f);
        float y1 = fmaxf((a1 - mean) * rstd * g0.y + e0.y, 0.0f);
        float y2 = fmaxf((a2 - mean) * rstd * g0.z + e0.z, 0.0f);
        float y3 = fmaxf((a3 - mean) * rstd * g0.w + e0.w, 0.0f);
        float y4 = fmaxf((a4 - mean) * rstd * g1.x + e1.x, 0.0f);
        float y5 = fmaxf((a5 - mean) * rstd * g1.y + e1.y, 0.0f);
        float y6 = fmaxf((a6 - mean) * rstd * g1.z + e1.z, 0.0f);
        float y7 = fmaxf((a7 - mean) * rstd * g1.w + e1.w, 0.0f);
        uint4v o;
        o.x = pack2(y0, y1);
        o.y = pack2(y2, y3);
        o.z = pack2(y4, y5);
        o.w = pack2(y6, y7);
        __builtin_nontemporal_store(o, (uint4v*)(xo + node * 256 + d8));
    }
}

__global__ __launch_bounds__(256) void k_lnrelu(const u16* __restrict__ h,
                                                const float* __restrict__ bias,
                                                const float* __restrict__ gamma,
                                                const float* __restrict__ beta,
                                                u16* __restrict__ xo) {
    int wave = threadIdx.x >> 6, lane = threadIdx.x & 63;
    int row = blockIdx.x * 4 + wave;
    int base = row * 256 + lane * 4;
    ushort4 hv = *(const ushort4*)(h + base);
    float4 bv = *(const float4*)(bias + lane * 4);
    float a0 = bf2f(hv.x) + bv.x, a1 = bf2f(hv.y) + bv.y;
    float a2 = bf2f(hv.z) + bv.z, a3 = bf2f(hv.w) + bv.w;
    float s1 = a0 + a1 + a2 + a3;
    float s2 = a0 * a0 + a1 * a1 + a2 * a2 + a3 * a3;
    for (int o = 32; o >= 1; o >>= 1) {
        s1 += __shfl_xor(s1, o, 64);
        s2 += __shfl_xor(s2, o, 64);
    }
    float mean = s1 * (1.0f / 256.0f);
    float var = s2 * (1.0f / 256.0f) - mean * mean;
    float rstd = rsqrtf(var + 1e-5f);
    float4 gv = *(const float4*)(gamma + lane * 4);
    float4 be = *(const float4*)(beta + lane * 4);
    float y0 = fmaxf((a0 - mean) * rstd * gv.x + be.x, 0.0f);
    float y1 = fmaxf((a1 - mean) * rstd * gv.y + be.y, 0.0f);
    float y2 = fmaxf((a2 - mean) * rstd * gv.z + be.z, 0.0f);
    float y3 = fmaxf((a3 - mean) * rstd * gv.w + be.w, 0.0f);
    ushort4 o4;
    o4.x = f2bf(y0); o4.y = f2bf(y1); o4.z = f2bf(y2); o4.w = f2bf(y3);
    *(ushort4*)(xo + base) = o4;
}

// ---- last layer: bias + LN + ReLU + [256x10] out-proj fused ----
__global__ __launch_bounds__(256) void k_lnout(const u16* __restrict__ h,
                                               const float* __restrict__ bias,
                                               const float* __restrict__ gamma,
                                               const float* __restrict__ beta,
                                               const float* __restrict__ W,
                                               const float* __restrict__ ob,
                                               float* __restrict__ out) {
    __shared__ float Ws[DD * NOUT];
    int tid = threadIdx.x;
    for (int i = tid; i < DD * NOUT; i += 256) Ws[i] = W[i];
    __syncthreads();
    int wave = tid >> 6, lane = tid & 63;
    int row = blockIdx.x * 4 + wave;
    int base = row * 256 + lane * 4;
    ushort4 hv = *(const ushort4*)(h + base);
    float4 bv = *(const float4*)(bias + lane * 4);
    float a0 = bf2f(hv.x) + bv.x, a1 = bf2f(hv.y) + bv.y;
    float a2 = bf2f(hv.z) + bv.z, a3 = bf2f(hv.w) + bv.w;
    float s1 = a0 + a1 + a2 + a3;
    float s2 = a0 * a0 + a1 * a1 + a2 * a2 + a3 * a3;
    for (int o = 32; o >= 1; o >>= 1) {
        s1 += __shfl_xor(s1, o, 64);
        s2 += __shfl_xor(s2, o, 64);
    }
    float mean = s1 * (1.0f / 256.0f);
    float var = s2 * (1.0f / 256.0f) - mean * mean;
    float rstd = rsqrtf(var + 1e-5f);
    float4 gv = *(const float4*)(gamma + lane * 4);
    float4 be = *(const float4*)(beta + lane * 4);
    // match reference numerics: y = bf16(relu(...)) then matmul
    float y0 = bf2f(f2bf(fmaxf((a0 - mean) * rstd * gv.x + be.x, 0.0f)));
    float y1 = bf2f(f2bf(fmaxf((a1 - mean) * rstd * gv.y + be.y, 0.0f)));
    float y2 = bf2f(f2bf(fmaxf((a2 - mean) * rstd * gv.z + be.z, 0.0f)));
    float y3 = bf2f(f2bf(fmaxf((a3 - mean) * rstd * gv.w + be.w, 0.0f)));
    int d = lane * 4;
    for (int o = 0; o < NOUT; o++) {
        float p = y0 * Ws[(d + 0) * NOUT + o] + y1 * Ws[(d + 1) * NOUT + o] +
                  y2 * Ws[(d + 2) * NOUT + o] + y3 * Ws[(d + 3) * NOUT + o];
        for (int off = 32; off >= 1; off >>= 1) p += __shfl_xor(p, off, 64);
        if (lane == 0) out[row * NOUT + o] = p + ob[o];
    }
}

extern "C" void kernel_launch(void* const* d_in, const int* in_sizes, int n_in,
                              void* d_out, int out_size, void* d_ws, size_t ws_size,
                              hipStream_t stream) {
    (void)in_sizes; (void)n_in; (void)out_size; (void)ws_size;
    const int* tokens = (const int*)d_in[0];
    const int* edges = (const int*)d_in[1];
    const int* tgt = (const int*)d_in[2];
    const float* emb = (const float*)d_in[3];
    const float* gnn_W = (const float*)d_in[4];
    const float* gnn_b = (const float*)d_in[5];
    const float* gnn_g = (const float*)d_in[6];
    const float* gnn_be = (const float*)d_in[7];
    const float* lin_W = (const float*)d_in[8];
    const float* lin_b = (const float*)d_in[9];
    const float* lin_g = (const float*)d_in[10];
    const float* lin_be = (const float*)d_in[11];
    const float* out_W = (const float*)d_in[12];
    const float* out_b = (const float*)d_in[13];
    float* out = (float*)d_out;

    char* ws = (char*)d_ws;
    u16* x = (u16*)ws;           ws += (size_t)NN * 256 * 2;
    // recs region (dead after csr build)
    char* hreg = ws;             ws += (size_t)NN * 256 * 2;
    int* recs = (int*)hreg;      // NE*4 = 12.8MB < 51.2MB
    u32* csrp = (u32*)ws;        ws += (size_t)CSRP_CAP * 4;
    int2* nodeInfo = (int2*)ws;  ws += (size_t)NN * 8;
    float* dinv = (float*)ws;    ws += (size_t)NN * 4;
    int* bucketCnt = (int*)ws;   ws += 256 * 4;
    int* bucketOff = (int*)ws;   ws += 256 * 4;
    int* bucketCur = (int*)ws;   ws += 256 * 4;
    u16* Wt = (u16*)ws;          ws += (size_t)6 * 65536 * 2;
    u16* xt = (u16*)ws;          ws += (size_t)NT * 256 * 2;
    u16* ht = (u16*)ws;          ws += (size_t)NT * 256 * 2;
    u8* q8 = (u8*)ws;            ws += (size_t)(NN + 64) * 256;
    float* qs = (float*)ws;      ws += (size_t)(NN + 64) * 4;  // [NN]

    const int* e_src = edges;
    const int* e_dst = edges + NE;

    k_wt<<<1536, 256, 0, stream>>>(gnn_W, lin_W, Wt, bucketCnt);
    k_binA<<<782, 256, 0, stream>>>(e_dst, bucketCnt);
    k_bscan<<<1, 256, 0, stream>>>(bucketCnt, bucketOff, bucketCur);
    k_binB<<<196, 1024, 0, stream>>>(e_src, e_dst, bucketCur, recs);
    k_csrA<<<NBUCK, 256, 0, stream>>>(recs, bucketOff, nodeInfo, dinv, csrp);
    k_csrB<<<NBUCK, 256, 0, stream>>>(recs, bucketOff, nodeInfo, dinv, csrp);

    for (int l = 0; l < 4; l++) {
        if (l == 0)
            k_gemm_embq<<<1563, 256, 0, stream>>>(tokens, emb, Wt,
                                                  q8, qs, NN);
        else
            k_gemmq<<<1563, 256, 0, stream>>>(x, Wt + l * 65536,
                                              q8, qs, NN);
        k_aggr<<<25000, 256, 0, stream>>>(q8, qs, nodeInfo, csrp,
                                          gnn_b + l * 256, gnn_g + l * 256,
                                          gnn_be + l * 256, x);
    }
    // lin layer 0: gather fused into GEMM A-staging
    k_gemm_gather<<<dim3(64, 2), 256, 0, stream>>>(x, tgt, Wt + 4 * 65536,
                                                   ht, NT);
    k_lnrelu<<<2048, 256, 0, stream>>>(ht, lin_b, lin_g, lin_be, xt);
    // lin layer 1: GEMM then LN+ReLU+out-proj fused
    k_gemm<<<dim3(64, 2), 256, 0, stream>>>(xt, Wt + 5 * 65536, ht, NT);
    k_lnout<<<2048, 256, 0, stream>>>(ht, lin_b + 256, lin_g + 256,
                                      lin_be + 256, out_W, out_b, out);
}

// Round 9
// 913.201 us; speedup vs baseline: 1.2431x; 1.0458x over previous
//
#include <hip/hip_runtime.h>
#include <hip/hip_fp16.h>

#define NN 100000
#define NE 3200000
#define DD 256
#define NT 8192
#define NOUT 10
#define NBUCK 196        // ceil(100000/512) buckets of 512 dst nodes
// per bucket: edges + 512 self + <=512*7 pad + 8 align slack
#define CSRP_CAP (NE + NBUCK * 4112 + 64)

typedef unsigned short u16;
typedef unsigned int u32;
typedef unsigned char u8;
typedef __attribute__((ext_vector_type(8))) short bf16x8;
typedef __attribute__((ext_vector_type(4))) float f32x4;
typedef __attribute__((ext_vector_type(4))) unsigned int uint4v;

__device__ __forceinline__ float bf2f(u16 u) {
    union { unsigned int i; float f; } v; v.i = ((unsigned int)u) << 16; return v.f;
}
__device__ __forceinline__ u16 f2bf(float f) {
    union { float f; unsigned int i; } v; v.f = f;
    unsigned int x = v.i;
    return (u16)((x + 0x7fffu + ((x >> 16) & 1u)) >> 16);
}
__device__ __forceinline__ unsigned int pack2(float a, float b) {
    return (unsigned int)f2bf(a) | ((unsigned int)f2bf(b) << 16);
}
// pack src(17b) | fp16-no-sign(15b); w>0 always
__device__ __forceinline__ u32 packrec(int src, float w) {
    unsigned short h = __half_as_ushort(__float2half(w));
    return ((u32)src << 15) | (u32)(h & 0x7fff);
}
__device__ __forceinline__ float recw(u32 r) {
    return __half2float(__ushort_as_half((unsigned short)(r & 0x7fff)));
}

__device__ __forceinline__ void gl2lds16(const void* g, void* l) {
    __builtin_amdgcn_global_load_lds(
        (const __attribute__((address_space(1))) unsigned int*)g,
        (__attribute__((address_space(3))) unsigned int*)l, 16, 0, 0);
}

// ---- weight convert + transpose: Wt[l][n][k] = bf16(W[l][k][n]) ----
// block 0 also zeroes bucketCnt (saves a dispatch)
__global__ __launch_bounds__(256) void k_wt(const float* __restrict__ gW,
                                            const float* __restrict__ lW,
                                            u16* __restrict__ Wt,
                                            int* __restrict__ bucketCnt) {
    if (blockIdx.x == 0 && threadIdx.x < NBUCK) bucketCnt[threadIdx.x] = 0;
    int idx = blockIdx.x * 256 + threadIdx.x;      // < 6*65536
    int l = idx >> 16;
    int nk = idx & 65535;
    int n = nk >> 8, k = nk & 255;
    float v = (l < 4) ? gW[l * 65536 + k * 256 + n]
                      : lW[(l - 4) * 65536 + k * 256 + n];
    Wt[idx] = f2bf(v);
}

// ---- pass A: per-bucket edge counts ----
__global__ __launch_bounds__(256) void k_binA(const int* __restrict__ dst,
                                              int* __restrict__ bucketCnt) {
    __shared__ int hist[NBUCK];
    int t = threadIdx.x;
    if (t < NBUCK) hist[t] = 0;
    __syncthreads();
    int base = blockIdx.x * 4096;
#pragma unroll
    for (int i = 0; i < 16; i++) {
        int e = base + i * 256 + t;
        if (e < NE) atomicAdd(&hist[dst[e] >> 9], 1);
    }
    __syncthreads();
    if (t < NBUCK && hist[t] > 0) atomicAdd(&bucketCnt[t], hist[t]);
}

// ---- scan bucket counts -> bucketOff (stable) + bucketCur (cursor) ----
__global__ __launch_bounds__(256) void k_bscan(const int* __restrict__ bucketCnt,
                                               int* __restrict__ bucketOff,
                                               int* __restrict__ bucketCur) {
    __shared__ int s[256];
    int t = threadIdx.x;
    int v = (t < NBUCK) ? bucketCnt[t] : 0;
    s[t] = v;
    __syncthreads();
    for (int o = 1; o < 256; o <<= 1) {
        int a = (t >= o) ? s[t - o] : 0;
        __syncthreads();
        s[t] += a;
        __syncthreads();
    }
    if (t < NBUCK) {
        int ex = s[t] - v;
        bucketOff[t] = ex;
        bucketCur[t] = ex;
    }
    if (t == 0) bucketOff[NBUCK] = NE;
}

// ---- pass B: write records at ABSOLUTE bucket offsets ----
// record = (src << 9) | (dst & 511)   (src < 2^17)
__global__ __launch_bounds__(1024) void k_binB(const int* __restrict__ src,
                                               const int* __restrict__ dst,
                                               int* __restrict__ bucketCur,
                                               int* __restrict__ recs) {
    __shared__ int hist[NBUCK];
    __shared__ int gbase[NBUCK];
    int t = threadIdx.x;
    if (t < NBUCK) hist[t] = 0;
    __syncthreads();
    int base = blockIdx.x * 16384;
    int recv[16], bks[16], rnk[16];
#pragma unroll
    for (int i = 0; i < 16; i++) {
        int e = base + i * 1024 + t;
        int bk = -1, rec = 0;
        if (e < NE) {
            int s_ = src[e], d_ = dst[e];
            bk = d_ >> 9;
            rec = (s_ << 9) | (d_ & 511);
        }
        bks[i] = bk; recv[i] = rec;
    }
#pragma unroll
    for (int i = 0; i < 16; i++)
        rnk[i] = (bks[i] >= 0) ? atomicAdd(&hist[bks[i]], 1) : 0;
    __syncthreads();
    if (t < NBUCK) {
        int c = hist[t];
        gbase[t] = (c > 0) ? atomicAdd(&bucketCur[t], c) : 0;  // absolute
    }
    __syncthreads();
#pragma unroll
    for (int i = 0; i < 16; i++)
        if (bks[i] >= 0) {
            int pos = gbase[bks[i]] + rnk[i];
            pos = min(max(pos, 0), NE - 1);
            recs[pos] = recv[i];
        }
}

// ---- csrA: per-bucket count + padded scan -> nodeInfo/dinv/self/dummies ----
// csrp record = u32 (src<<15)|fp16w; per node: [self][edges...][dummies] pad 8
// NOTE: must be a SEPARATE dispatch from csrB — csrB reads dinv[s] for
// arbitrary s (cross-bucket); merging creates a cross-workgroup RAW race (R9).
__global__ __launch_bounds__(256) void k_csrA(const int* __restrict__ recs,
                                              const int* __restrict__ bucketOff,
                                              int2* __restrict__ nodeInfo,
                                              float* __restrict__ dinv,
                                              u32* __restrict__ csrp) {
    __shared__ int cnt[512], off[512];
    int b = blockIdx.x, t = threadIdx.x;
    int beg = min(max(bucketOff[b], 0), NE);
    int end = min(max(bucketOff[b + 1], beg), NE);
    int n = end - beg;
    cnt[t] = 0; cnt[t + 256] = 0;
    __syncthreads();
    for (int i = t; i < n; i += 256)
        atomicAdd(&cnt[recs[beg + i] & 511], 1);
    __syncthreads();
    off[t] = (cnt[t] + 8) & ~7;            // padded size: cnt+1 self, round to 8
    off[t + 256] = (cnt[t + 256] + 8) & ~7;
    __syncthreads();
    for (int o = 1; o < 512; o <<= 1) {
        int v0 = (t >= o) ? off[t - o] : 0;
        int v1 = (t + 256 >= o) ? off[t + 256 - o] : 0;
        __syncthreads();
        off[t] += v0; off[t + 256] += v1;
        __syncthreads();
    }
    int base = (beg + b * 4112 + 7) & ~7;  // 8-record aligned bucket region
    for (int k = t; k < 512; k += 256) {
        int node = b * 512 + k;
        if (node >= NN) continue;
        int pd = (cnt[k] + 8) & ~7;
        int nbeg = base + off[k] - pd;     // exclusive padded scan (8-aligned)
        int2 ni; ni.x = nbeg; ni.y = pd;
        nodeInfo[node] = ni;
        float di = rsqrtf((float)(cnt[k] + 1));
        dinv[node] = di;
        csrp[nbeg] = packrec(node, di * di);
        for (int j = nbeg + 1 + cnt[k]; j < nbeg + pd; j++) csrp[j] = 0u;
    }
}

// ---- csrB: scatter edges with precomputed fp16 weight ----
__global__ __launch_bounds__(256) void k_csrB(const int* __restrict__ recs,
                                              const int* __restrict__ bucketOff,
                                              const int2* __restrict__ nodeInfo,
                                              const float* __restrict__ dinv,
                                              u32* __restrict__ csrp) {
    __shared__ int cur[512];
    int b = blockIdx.x, t = threadIdx.x;
    cur[t] = 0; cur[t + 256] = 0;
    __syncthreads();
    int beg = min(max(bucketOff[b], 0), NE);
    int end = min(max(bucketOff[b + 1], beg), NE);
    int n = end - beg;
    for (int i = t; i < n; i += 256) {
        int r = recs[beg + i];
        int dlow = r & 511;
        int s = min(max(r >> 9, 0), NN - 1);
        int node = b * 512 + dlow;
        int rk = atomicAdd(&cur[dlow], 1);
        int2 ni = nodeInfo[node];
        float w = dinv[s] * dinv[node];
        int pos = ni.x + 1 + rk;
        pos = min(max(pos, 0), CSRP_CAP - 1);
        csrp[pos] = packrec(s, w);
    }
}

// ---- shared GEMM epilogue (bf16 C) — lin-layer 128x128 kernels ----
#define GEMM_EPILOGUE                                                         \
    for (int i = 0; i < 4; i++)                                               \
        for (int j = 0; j < 4; j++) {                                         \
            int col = colBase + wn * 64 + j * 16 + l16;                       \
            for (int r = 0; r < 4; r++) {                                     \
                int row = rowBase + wm * 64 + i * 16 + quad * 4 + r;          \
                if (row < M) C[row * 256 + col] = f2bf(acc[i][j][r]);         \
            }                                                                 \
        }

#define GEMM_COMPUTE(ASRC, BSRC)                                              \
    for (int ks = 0; ks < 2; ks++) {                                          \
        bf16x8 a_frag[4], b_frag[4];                                          \
        for (int i = 0; i < 4; i++) {                                         \
            int r = wm * 64 + i * 16 + l16;                                   \
            int ch = (ks * 4 + quad) ^ (r & 7);                               \
            a_frag[i] = *(const bf16x8*)(&ASRC[r * 64 + ch * 8]);             \
        }                                                                     \
        for (int j = 0; j < 4; j++) {                                         \
            int r = wn * 64 + j * 16 + l16;                                   \
            int ch = (ks * 4 + quad) ^ (r & 7);                               \
            b_frag[j] = *(const bf16x8*)(&BSRC[r * 64 + ch * 8]);             \
        }                                                                     \
        for (int i = 0; i < 4; i++)                                           \
            for (int j = 0; j < 4; j++)                                       \
                acc[i][j] = __builtin_amdgcn_mfma_f32_16x16x32_bf16(          \
                    a_frag[i], b_frag[j], acc[i][j], 0, 0, 0);                \
    }

// ---- GNN GEMM compute for 128x256 tile (8 waves: wr=wave>>2, wc=wave&3) ----
#define GEMMQ_COMPUTE                                                         \
    for (int ks = 0; ks < 2; ks++) {                                          \
        bf16x8 a_frag[4], b_frag[4];                                          \
        for (int i = 0; i < 4; i++) {                                         \
            int r = wr * 64 + i * 16 + l16;                                   \
            int ch = (ks * 4 + quad) ^ (r & 7);                               \
            a_frag[i] = *(const bf16x8*)(&As[r * 64 + ch * 8]);               \
        }                                                                     \
        for (int j = 0; j < 4; j++) {                                         \
            int r = wc * 64 + j * 16 + l16;                                   \
            int ch = (ks * 4 + quad) ^ (r & 7);                               \
            b_frag[j] = *(const bf16x8*)(&Bs[r * 64 + ch * 8]);               \
        }                                                                     \
        for (int i = 0; i < 4; i++)                                           \
            for (int j = 0; j < 4; j++)                                       \
                acc[i][j] = __builtin_amdgcn_mfma_f32_16x16x32_bf16(          \
                    a_frag[i], b_frag[j], acc[i][j], 0, 0, 0);                \
    }

// ---- quant epilogue 128x256: SINGLE per-row scale over all 256 cols ->
// int8 bytes + qs[NN]. rowmax planes through As (dead), bytes through Bs. ----
#define QUANTQ_EPILOGUE(Q8, QS)                                               \
    {                                                                         \
        float* rowmaxLDS = (float*)As;        /* [4][128] = 2 KB */           \
        for (int i = 0; i < 4; i++)                                           \
            for (int r = 0; r < 4; r++) {                                     \
                float m = 0.f;                                                \
                for (int j = 0; j < 4; j++)                                   \
                    m = fmaxf(m, fabsf(acc[i][j][r]));                        \
                m = fmaxf(m, __shfl_xor(m, 1, 64));                           \
                m = fmaxf(m, __shfl_xor(m, 2, 64));                           \
                m = fmaxf(m, __shfl_xor(m, 4, 64));                           \
                m = fmaxf(m, __shfl_xor(m, 8, 64));                           \
                if (l16 == 0)                                                 \
                    rowmaxLDS[wc * 128 + wr * 64 + i * 16 + quad * 4 + r] = m;\
            }                                                                 \
        __syncthreads();                                                      \
        u8* bb = (u8*)Bs;                      /* [128][256] = 32 KB */       \
        for (int i = 0; i < 4; i++)                                           \
            for (int r = 0; r < 4; r++) {                                     \
                int rl = wr * 64 + i * 16 + quad * 4 + r;                     \
                float m = fmaxf(fmaxf(rowmaxLDS[rl], rowmaxLDS[128 + rl]),    \
                                fmaxf(rowmaxLDS[256 + rl],                    \
                                      rowmaxLDS[384 + rl]));                  \
                if (wc == 0 && l16 == 0) {                                    \
                    int row = rowBase + rl;                                   \
                    if (row < M) QS[row] = m * (1.0f / 126.0f);               \
                }                                                             \
                float inv = m > 0.f ? 126.f / m : 0.f;                        \
                for (int j = 0; j < 4; j++)                                   \
                    bb[rl * 256 + wc * 64 + j * 16 + l16] =                   \
                        (u8)((int)rintf(acc[i][j][r] * inv) + 128);           \
            }                                                                 \
        __syncthreads();                                                      \
        for (int u = 0; u < 4; u++) {                                         \
            int id = u * 512 + tid;                                           \
            int rl = id >> 4, c16 = (id & 15) * 16;                           \
            int row = rowBase + rl;                                           \
            if (row < M)                                                      \
                *(uint4*)(Q8 + (size_t)row * 256 + c16) =                     \
                    *(const uint4*)(bb + rl * 256 + c16);                     \
        }                                                                     \
    }

// ---- bf16 MFMA GEMM (bf16 C out) — lin layers, 128x128 tile ----
__global__ __launch_bounds__(256) void k_gemm(const u16* __restrict__ A,
                                              const u16* __restrict__ Bt,
                                              u16* __restrict__ C, int M) {
    __shared__ __align__(16) u16 As[128 * 64];
    __shared__ __align__(16) u16 Bs[128 * 64];
    const int tid = threadIdx.x;
    const int wave = tid >> 6, lane = tid & 63;
    const int wm = wave >> 1, wn = wave & 1;
    const int rowBase = blockIdx.x * 128;
    const int colBase = blockIdx.y * 128;
    const int quad = lane >> 4, l16 = lane & 15;

    f32x4 acc[4][4] = {};

    for (int kk = 0; kk < 4; kk++) {
        int k0 = kk * 64;
#pragma unroll
        for (int i = 0; i < 4; i++) {
            int j = (i * 4 + wave) * 64 + lane;    // task 0..1023
            int r = j >> 3, c = j & 7;
            int cg = c ^ (r & 7);                  // source-chunk swizzle
            int ga = rowBase + r; if (ga >= M) ga = M - 1;
            gl2lds16(A + (size_t)ga * 256 + k0 + cg * 8,
                     &As[(i * 4 + wave) * 512]);
            gl2lds16(Bt + (size_t)(colBase + r) * 256 + k0 + cg * 8,
                     &Bs[(i * 4 + wave) * 512]);
        }
        __syncthreads();
        GEMM_COMPUTE(As, Bs)
        __syncthreads();
    }
    GEMM_EPILOGUE
}

// ---- GNN GEMM: 128x256 tile, 512 thr, LDS-staged, fused int8-quant ----
__global__ __launch_bounds__(512) void k_gemmq(const u16* __restrict__ A,
                                               const u16* __restrict__ Bt,
                                               u8* __restrict__ q8,
                                               float* __restrict__ qs, int M) {
    __shared__ __align__(16) u16 As[128 * 64];     // 16 KB
    __shared__ __align__(16) u16 Bs[256 * 64];     // 32 KB
    const int tid = threadIdx.x;
    const int wave = tid >> 6, lane = tid & 63;
    const int wr = wave >> 2, wc = wave & 3;
    const int rowBase = blockIdx.x * 128;
    const int quad = lane >> 4, l16 = lane & 15;

    f32x4 acc[4][4] = {};

    for (int kk = 0; kk < 4; kk++) {
        int k0 = kk * 64;
#pragma unroll
        for (int i = 0; i < 2; i++) {              // A: 128 rows x 64 k
            int j = (i * 8 + wave) * 64 + lane;    // tasks 0..1023
            int r = j >> 3, c = j & 7;
            int cg = c ^ (r & 7);
            int ga = rowBase + r; if (ga >= M) ga = M - 1;
            gl2lds16(A + (size_t)ga * 256 + k0 + cg * 8,
                     &As[(i * 8 + wave) * 512]);
        }
#pragma unroll
        for (int i = 0; i < 4; i++) {              // B: 256 n x 64 k
            int j = (i * 8 + wave) * 64 + lane;    // tasks 0..2047
            int r = j >> 3, c = j & 7;
            int cg = c ^ (r & 7);
            gl2lds16(Bt + (size_t)r * 256 + k0 + cg * 8,
                     &Bs[(i * 8 + wave) * 512]);
        }
        __syncthreads();
        GEMMQ_COMPUTE
        __syncthreads();
    }
    QUANTQ_EPILOGUE(q8, qs)
}

// ---- GNN GEMM layer 0: 128x256 tile, A gathered from f32 emb, fused quant ----
__global__ __launch_bounds__(512) void k_gemm_embq(const int* __restrict__ tokens,
                                                   const float* __restrict__ emb,
                                                   const u16* __restrict__ Bt,
                                                   u8* __restrict__ q8,
                                                   float* __restrict__ qs, int M) {
    __shared__ __align__(16) u16 As[128 * 64];
    __shared__ __align__(16) u16 Bs[256 * 64];
    __shared__ int tokLDS[128];
    const int tid = threadIdx.x;
    const int wave = tid >> 6, lane = tid & 63;
    const int wr = wave >> 2, wc = wave & 3;
    const int rowBase = blockIdx.x * 128;
    const int quad = lane >> 4, l16 = lane & 15;

    if (tid < 128) {
        int ga = rowBase + tid; if (ga >= M) ga = M - 1;
        tokLDS[tid] = tokens[ga];
    }
    f32x4 acc[4][4] = {};
    __syncthreads();

    for (int kk = 0; kk < 4; kk++) {
        int k0 = kk * 64;
#pragma unroll
        for (int i = 0; i < 2; i++) {              // A: gather f32 emb rows
            int j = i * 512 + tid;                 // tasks 0..1023
            int r = j >> 3, c = j & 7;
            int cg = c ^ (r & 7);
            const float* srcp = emb + (size_t)tokLDS[r] * 256 + k0 + cg * 8;
            float4 f0 = *(const float4*)srcp;
            float4 f1 = *(const float4*)(srcp + 4);
            uint4 pk;
            pk.x = pack2(f0.x, f0.y); pk.y = pack2(f0.z, f0.w);
            pk.z = pack2(f1.x, f1.y); pk.w = pack2(f1.z, f1.w);
            *(uint4*)(&As[j * 8]) = pk;
        }
#pragma unroll
        for (int i = 0; i < 4; i++) {              // B: 256 n x 64 k
            int j = (i * 8 + wave) * 64 + lane;
            int r = j >> 3, c = j & 7;
            int cg = c ^ (r & 7);
            gl2lds16(Bt + (size_t)r * 256 + k0 + cg * 8,
                     &Bs[(i * 8 + wave) * 512]);
        }
        __syncthreads();
        GEMMQ_COMPUTE
        __syncthreads();
    }
    QUANTQ_EPILOGUE(q8, qs)
}

// ---- lin GEMM-1: A rows gathered from x via tgt (k_gather fused) ----
__global__ __launch_bounds__(256) void k_gemm_gather(const u16* __restrict__ X,
                                                     const int* __restrict__ tgt,
                                                     const u16* __restrict__ Bt,
                                                     u16* __restrict__ C, int M) {
    __shared__ __align__(16) u16 As[128 * 64];
    __shared__ __align__(16) u16 Bs[128 * 64];
    __shared__ int rowLDS[128];
    const int tid = threadIdx.x;
    const int wave = tid >> 6, lane = tid & 63;
    const int wm = wave >> 1, wn = wave & 1;
    const int rowBase = blockIdx.x * 128;
    const int colBase = blockIdx.y * 128;
    const int quad = lane >> 4, l16 = lane & 15;

    if (tid < 128) {
        int ga = rowBase + tid; if (ga >= M) ga = M - 1;
        rowLDS[tid] = tgt[ga];
    }
    f32x4 acc[4][4] = {};
    __syncthreads();

    for (int kk = 0; kk < 4; kk++) {
        int k0 = kk * 64;
#pragma unroll
        for (int i = 0; i < 4; i++) {
            int j = (i * 4 + wave) * 64 + lane;
            int r = j >> 3, c = j & 7;
            int cg = c ^ (r & 7);
            uint4 v = *(const uint4*)(X + (size_t)rowLDS[r] * 256 + k0 + cg * 8);
            *(uint4*)(&As[j * 8]) = v;
            gl2lds16(Bt + (size_t)(colBase + r) * 256 + k0 + cg * 8,
                     &Bs[(i * 4 + wave) * 512]);
        }
        __syncthreads();
        GEMM_COMPUTE(As, Bs)
        __syncthreads();
    }
    GEMM_EPILOGUE
}

// ---- fused aggregate + bias + LN + ReLU over int8 rows ----
// R2's proven lean shape: 8 dims/lane, fp16 weight in record,
// SINGLE per-row scale qs[s] (wave-uniform base -> broadcast load)
#define GF8(RR, Q0, Q1, Q2, Q3, W0, W1, W2, W3)                               \
    {                                                                         \
        int s0 = (int)(RR.x >> 15), s1 = (int)(RR.y >> 15);                   \
        int s2 = (int)(RR.z >> 15), s3 = (int)(RR.w >> 15);                   \
        Q0 = *(const uint2*)(qb + (size_t)s0 * 256);                          \
        Q1 = *(const uint2*)(qb + (size_t)s1 * 256);                          \
        Q2 = *(const uint2*)(qb + (size_t)s2 * 256);                          \
        Q3 = *(const uint2*)(qb + (size_t)s3 * 256);                          \
        W0 = recw(RR.x) * qs[s0]; W1 = recw(RR.y) * qs[s1];                   \
        W2 = recw(RR.z) * qs[s2]; W3 = recw(RR.w) * qs[s3];                   \
    }

#define GC8_ONE(Q, W)                                                         \
    {                                                                         \
        Ks += W;                                                              \
        a0 = fmaf(W, (float)(Q.x & 255u), a0);                                \
        a1 = fmaf(W, (float)((Q.x >> 8) & 255u), a1);                         \
        a2 = fmaf(W, (float)((Q.x >> 16) & 255u), a2);                        \
        a3 = fmaf(W, (float)(Q.x >> 24), a3);                                 \
        a4 = fmaf(W, (float)(Q.y & 255u), a4);                                \
        a5 = fmaf(W, (float)((Q.y >> 8) & 255u), a5);                         \
        a6 = fmaf(W, (float)((Q.y >> 16) & 255u), a6);                        \
        a7 = fmaf(W, (float)(Q.y >> 24), a7);                                 \
    }

__global__ __launch_bounds__(256) void k_aggr(const u8* __restrict__ q8,
                                              const float* __restrict__ qs,
                                              const int2* __restrict__ nodeInfo,
                                              const u32* __restrict__ csrp,
                                              const float* __restrict__ bias,
                                              const float* __restrict__ gamma,
                                              const float* __restrict__ beta,
                                              u16* __restrict__ xo) {
    const int wave = threadIdx.x >> 6, lane = threadIdx.x & 63;
    const int half = lane >> 5, l32 = lane & 31;
    const int node = blockIdx.x * 4 + wave;
    const int d8 = l32 * 8;                  // 8 dims per lane
    int2 ni = nodeInfo[node];
    float a0=0,a1=0,a2=0,a3=0,a4=0,a5=0,a6=0,a7=0;
    float Ks = 0.0f;
    const u8* qb = q8 + d8;
    const u32* cp = csrp + ni.x + half * 4;
    const int nrec = ni.y;
    int j = 0;
    for (; j + 16 <= nrec; j += 16, cp += 16) {
        uint4v ra = __builtin_nontemporal_load((const uint4v*)cp);
        uint4v rb = __builtin_nontemporal_load((const uint4v*)(cp + 8));
        uint2 qa0, qa1, qa2, qa3, qb0, qb1, qb2, qb3;
        float wa0, wa1, wa2, wa3, wb0, wb1, wb2, wb3;
        GF8(ra, qa0, qa1, qa2, qa3, wa0, wa1, wa2, wa3);
        GF8(rb, qb0, qb1, qb2, qb3, wb0, wb1, wb2, wb3);
        GC8_ONE(qa0, wa0); GC8_ONE(qa1, wa1);
        GC8_ONE(qa2, wa2); GC8_ONE(qa3, wa3);
        GC8_ONE(qb0, wb0); GC8_ONE(qb1, wb1);
        GC8_ONE(qb2, wb2); GC8_ONE(qb3, wb3);
    }
    if (j < nrec) {                          // nrec % 16 == 8 tail
        uint4v ra = __builtin_nontemporal_load((const uint4v*)cp);
        uint2 qa0, qa1, qa2, qa3;
        float wa0, wa1, wa2, wa3;
        GF8(ra, qa0, qa1, qa2, qa3, wa0, wa1, wa2, wa3);
        GC8_ONE(qa0, wa0); GC8_ONE(qa1, wa1);
        GC8_ONE(qa2, wa2); GC8_ONE(qa3, wa3);
    }
    a0 += __shfl_xor(a0, 32, 64); a1 += __shfl_xor(a1, 32, 64);
    a2 += __shfl_xor(a2, 32, 64); a3 += __shfl_xor(a3, 32, 64);
    a4 += __shfl_xor(a4, 32, 64); a5 += __shfl_xor(a5, 32, 64);
    a6 += __shfl_xor(a6, 32, 64); a7 += __shfl_xor(a7, 32, 64);
    Ks += __shfl_xor(Ks, 32, 64);
    float c128 = 128.0f * Ks;
    a0 -= c128; a1 -= c128; a2 -= c128; a3 -= c128;
    a4 -= c128; a5 -= c128; a6 -= c128; a7 -= c128;

    float4 b0 = *(const float4*)(bias + d8);
    float4 b1 = *(const float4*)(bias + d8 + 4);
    a0 += b0.x; a1 += b0.y; a2 += b0.z; a3 += b0.w;
    a4 += b1.x; a5 += b1.y; a6 += b1.z; a7 += b1.w;
    float s1 = a0+a1+a2+a3+a4+a5+a6+a7;
    float s2 = a0*a0+a1*a1+a2*a2+a3*a3+a4*a4+a5*a5+a6*a6+a7*a7;
    for (int o = 16; o >= 1; o >>= 1) {
        s1 += __shfl_xor(s1, o, 64);
        s2 += __shfl_xor(s2, o, 64);
    }
    float mean = s1 * (1.0f / 256.0f);
    float var = s2 * (1.0f / 256.0f) - mean * mean;
    float rstd = rsqrtf(var + 1e-5f);
    if (half == 0) {
        float4 g0 = *(const float4*)(gamma + d8);
        float4 g1 = *(const float4*)(gamma + d8 + 4);
        float4 e0 = *(const float4*)(beta + d8);
        float4 e1 = *(const float4*)(beta + d8 + 4);
        float y0 = fmaxf((a0 - mean) * rstd * g0.x + e0.x, 0.0f);
        float y1 = fmaxf((a1 - mean) * rstd * g0.y + e0.y, 0.0f);
        float y2 = fmaxf((a2 - mean) * rstd * g0.z + e0.z, 0.0f);
        float y3 = fmaxf((a3 - mean) * rstd * g0.w + e0.w, 0.0f);
        float y4 = fmaxf((a4 - mean) * rstd * g1.x + e1.x, 0.0f);
        float y5 = fmaxf((a5 - mean) * rstd * g1.y + e1.y, 0.0f);
        float y6 = fmaxf((a6 - mean) * rstd * g1.z + e1.z, 0.0f);
        float y7 = fmaxf((a7 - mean) * rstd * g1.w + e1.w, 0.0f);
        uint4v o;
        o.x = pack2(y0, y1);
        o.y = pack2(y2, y3);
        o.z = pack2(y4, y5);
        o.w = pack2(y6, y7);
        __builtin_nontemporal_store(o, (uint4v*)(xo + node * 256 + d8));
    }
}

__global__ __launch_bounds__(256) void k_lnrelu(const u16* __restrict__ h,
                                                const float* __restrict__ bias,
                                                const float* __restrict__ gamma,
                                                const float* __restrict__ beta,
                                                u16* __restrict__ xo) {
    int wave = threadIdx.x >> 6, lane = threadIdx.x & 63;
    int row = blockIdx.x * 4 + wave;
    int base = row * 256 + lane * 4;
    ushort4 hv = *(const ushort4*)(h + base);
    float4 bv = *(const float4*)(bias + lane * 4);
    float a0 = bf2f(hv.x) + bv.x, a1 = bf2f(hv.y) + bv.y;
    float a2 = bf2f(hv.z) + bv.z, a3 = bf2f(hv.w) + bv.w;
    float s1 = a0 + a1 + a2 + a3;
    float s2 = a0 * a0 + a1 * a1 + a2 * a2 + a3 * a3;
    for (int o = 32; o >= 1; o >>= 1) {
        s1 += __shfl_xor(s1, o, 64);
        s2 += __shfl_xor(s2, o, 64);
    }
    float mean = s1 * (1.0f / 256.0f);
    float var = s2 * (1.0f / 256.0f) - mean * mean;
    float rstd = rsqrtf(var + 1e-5f);
    float4 gv = *(const float4*)(gamma + lane * 4);
    float4 be = *(const float4*)(beta + lane * 4);
    float y0 = fmaxf((a0 - mean) * rstd * gv.x + be.x, 0.0f);
    float y1 = fmaxf((a1 - mean) * rstd * gv.y + be.y, 0.0f);
    float y2 = fmaxf((a2 - mean) * rstd * gv.z + be.z, 0.0f);
    float y3 = fmaxf((a3 - mean) * rstd * gv.w + be.w, 0.0f);
    ushort4 o4;
    o4.x = f2bf(y0); o4.y = f2bf(y1); o4.z = f2bf(y2); o4.w = f2bf(y3);
    *(ushort4*)(xo + base) = o4;
}

// ---- last layer: bias + LN + ReLU + [256x10] out-proj fused ----
__global__ __launch_bounds__(256) void k_lnout(const u16* __restrict__ h,
                                               const float* __restrict__ bias,
                                               const float* __restrict__ gamma,
                                               const float* __restrict__ beta,
                                               const float* __restrict__ W,
                                               const float* __restrict__ ob,
                                               float* __restrict__ out) {
    __shared__ float Ws[DD * NOUT];
    int tid = threadIdx.x;
    for (int i = tid; i < DD * NOUT; i += 256) Ws[i] = W[i];
    __syncthreads();
    int wave = tid >> 6, lane = tid & 63;
    int row = blockIdx.x * 4 + wave;
    int base = row * 256 + lane * 4;
    ushort4 hv = *(const ushort4*)(h + base);
    float4 bv = *(const float4*)(bias + lane * 4);
    float a0 = bf2f(hv.x) + bv.x, a1 = bf2f(hv.y) + bv.y;
    float a2 = bf2f(hv.z) + bv.z, a3 = bf2f(hv.w) + bv.w;
    float s1 = a0 + a1 + a2 + a3;
    float s2 = a0 * a0 + a1 * a1 + a2 * a2 + a3 * a3;
    for (int o = 32; o >= 1; o >>= 1) {
        s1 += __shfl_xor(s1, o, 64);
        s2 += __shfl_xor(s2, o, 64);
    }
    float mean = s1 * (1.0f / 256.0f);
    float var = s2 * (1.0f / 256.0f) - mean * mean;
    float rstd = rsqrtf(var + 1e-5f);
    float4 gv = *(const float4*)(gamma + lane * 4);
    float4 be = *(const float4*)(beta + lane * 4);
    // match reference numerics: y = bf16(relu(...)) then matmul
    float y0 = bf2f(f2bf(fmaxf((a0 - mean) * rstd * gv.x + be.x, 0.0f)));
    float y1 = bf2f(f2bf(fmaxf((a1 - mean) * rstd * gv.y + be.y, 0.0f)));
    float y2 = bf2f(f2bf(fmaxf((a2 - mean) * rstd * gv.z + be.z, 0.0f)));
    float y3 = bf2f(f2bf(fmaxf((a3 - mean) * rstd * gv.w + be.w, 0.0f)));
    int d = lane * 4;
    for (int o = 0; o < NOUT; o++) {
        float p = y0 * Ws[(d + 0) * NOUT + o] + y1 * Ws[(d + 1) * NOUT + o] +
                  y2 * Ws[(d + 2) * NOUT + o] + y3 * Ws[(d + 3) * NOUT + o];
        for (int off = 32; off >= 1; off >>= 1) p += __shfl_xor(p, off, 64);
        if (lane == 0) out[row * NOUT + o] = p + ob[o];
    }
}

extern "C" void kernel_launch(void* const* d_in, const int* in_sizes, int n_in,
                              void* d_out, int out_size, void* d_ws, size_t ws_size,
                              hipStream_t stream) {
    (void)in_sizes; (void)n_in; (void)out_size; (void)ws_size;
    const int* tokens = (const int*)d_in[0];
    const int* edges = (const int*)d_in[1];
    const int* tgt = (const int*)d_in[2];
    const float* emb = (const float*)d_in[3];
    const float* gnn_W = (const float*)d_in[4];
    const float* gnn_b = (const float*)d_in[5];
    const float* gnn_g = (const float*)d_in[6];
    const float* gnn_be = (const float*)d_in[7];
    const float* lin_W = (const float*)d_in[8];
    const float* lin_b = (const float*)d_in[9];
    const float* lin_g = (const float*)d_in[10];
    const float* lin_be = (const float*)d_in[11];
    const float* out_W = (const float*)d_in[12];
    const float* out_b = (const float*)d_in[13];
    float* out = (float*)d_out;

    char* ws = (char*)d_ws;
    u16* x = (u16*)ws;           ws += (size_t)NN * 256 * 2;
    // recs region (dead after csr build)
    char* hreg = ws;             ws += (size_t)NN * 256 * 2;
    int* recs = (int*)hreg;      // NE*4 = 12.8MB < 51.2MB
    u32* csrp = (u32*)ws;        ws += (size_t)CSRP_CAP * 4;
    int2* nodeInfo = (int2*)ws;  ws += (size_t)NN * 8;
    float* dinv = (float*)ws;    ws += (size_t)NN * 4;
    int* bucketCnt = (int*)ws;   ws += 256 * 4;
    int* bucketOff = (int*)ws;   ws += 256 * 4;
    int* bucketCur = (int*)ws;   ws += 256 * 4;
    u16* Wt = (u16*)ws;          ws += (size_t)6 * 65536 * 2;
    u16* xt = (u16*)ws;          ws += (size_t)NT * 256 * 2;
    u16* ht = (u16*)ws;          ws += (size_t)NT * 256 * 2;
    u8* q8 = (u8*)ws;            ws += (size_t)(NN + 128) * 256;
    float* qs = (float*)ws;      ws += (size_t)(NN + 128) * 4;  // [NN]

    const int* e_src = edges;
    const int* e_dst = edges + NE;

    k_wt<<<1536, 256, 0, stream>>>(gnn_W, lin_W, Wt, bucketCnt);
    k_binA<<<782, 256, 0, stream>>>(e_dst, bucketCnt);
    k_bscan<<<1, 256, 0, stream>>>(bucketCnt, bucketOff, bucketCur);
    k_binB<<<196, 1024, 0, stream>>>(e_src, e_dst, bucketCur, recs);
    k_csrA<<<NBUCK, 256, 0, stream>>>(recs, bucketOff, nodeInfo, dinv, csrp);
    k_csrB<<<NBUCK, 256, 0, stream>>>(recs, bucketOff, nodeInfo, dinv, csrp);

    for (int l = 0; l < 4; l++) {
        if (l == 0)
            k_gemm_embq<<<782, 512, 0, stream>>>(tokens, emb, Wt,
                                                 q8, qs, NN);
        else
            k_gemmq<<<782, 512, 0, stream>>>(x, Wt + l * 65536,
                                             q8, qs, NN);
        k_aggr<<<25000, 256, 0, stream>>>(q8, qs, nodeInfo, csrp,
                                          gnn_b + l * 256, gnn_g + l * 256,
                                          gnn_be + l * 256, x);
    }
    // lin layer 0: gather fused into GEMM A-staging
    k_gemm_gather<<<dim3(64, 2), 256, 0, stream>>>(x, tgt, Wt + 4 * 65536,
                                                   ht, NT);
    k_lnrelu<<<2048, 256, 0, stream>>>(ht, lin_b, lin_g, lin_be, xt);
    // lin layer 1: GEMM then LN+ReLU+out-proj fused
    k_gemm<<<dim3(64, 2), 256, 0, stream>>>(xt, Wt + 5 * 65536, ht, NT);
    k_lnout<<<2048, 256, 0, stream>>>(ht, lin_b + 256, lin_g + 256,
                                      lin_be + 256, out_W, out_b, out);
}